// Round 1
// 2920.019 us; speedup vs baseline: 1.0948x; 1.0948x over previous
//
#include <hip/hip_runtime.h>
#include <cstdint>
#include <cstddef>

// Problem constants: V=50000, E=300, NF=1, H=256, B=128, TH=32, TB=512, NC=4.
#define H_    256
#define NG    768      // 512 gate cols (r|u) + 256 candidate cols, packed
#define BATCH 128
#define TH_   32
#define TB_   512
#define E_    300
#define RPB   16             // batch rows per gru block
#define NBLK  (BATCH / RPB)  // 8 row-groups per job; fused grid = 24 blocks (3 jobs)

typedef _Float16 half8 __attribute__((ext_vector_type(8)));
typedef float    floatx4 __attribute__((ext_vector_type(4)));

#define AS1 __attribute__((address_space(1)))
#define AS3 __attribute__((address_space(3)))

// s_waitcnt immediates (gfx9 encoding: vmcnt[3:0]=imm[3:0], vmcnt[5:4]=imm[15:14],
// expcnt=imm[6:4], lgkmcnt=imm[11:8]).
#define WC_LGKM0 0xC07F   // lgkmcnt(0), vmcnt/exp unconstrained
#define WC_VM14  0x0F7E   // vmcnt(14) only
#define WC_VM6   0x0F76   // vmcnt(6)  only
#define WC_VM0   0x0F70   // vmcnt(0)  only

// ---------------------------------------------------------------------------
// bias[j] = [bg | bc] (768)
// ---------------------------------------------------------------------------
__global__ __launch_bounds__(256) void pack_bias(
    const float* __restrict__ bg, const float* __restrict__ bc,
    float* __restrict__ bias)
{
  int idx = blockIdx.x * 256 + threadIdx.x;
  if (idx < NG) bias[idx] = (idx < 2 * H_) ? bg[idx] : bc[idx - 2 * H_];
}

// ---------------------------------------------------------------------------
// Pack INPUT-projection weights into fp16 MFMA B-frag tiles for gemm_mfma.
// Global layout [kt][nt][lane][8]: tile (nt 0..47, kt 0..KT-1) holds
// B[k = kt*32 + (l>>4)*8 + j][col = nt*16 + (l&15)], zero-padded k>=din.
// col<512 -> Wg, else Wc col-512.
// ---------------------------------------------------------------------------
__global__ __launch_bounds__(256) void pack_bx(
    const float* __restrict__ Wg, const float* __restrict__ Wc,
    int din, int KT, _Float16* __restrict__ out)
{
  int idx = blockIdx.x * 256 + threadIdx.x;
  if (idx >= KT * 48 * 64) return;
  int lane = idx & 63, tile = idx >> 6;
  int kt = tile / 48, nt = tile - kt * 48;
  int col = nt * 16 + (lane & 15);
  int k0 = kt * 32 + (lane >> 4) * 8;
  const float* W; int ncols, c2;
  if (col < 2 * H_) { W = Wg; ncols = 2 * H_; c2 = col; }
  else              { W = Wc; ncols = H_;     c2 = col - 2 * H_; }
  _Float16* dst = out + ((size_t)(kt * 48 + nt) * 64 + lane) * 8;
#pragma unroll
  for (int j = 0; j < 8; ++j) {
    int k = k0 + j;
    dst[j] = (k < din) ? (_Float16)W[(size_t)k * ncols + c2] : (_Float16)0.f;
  }
}

// ---------------------------------------------------------------------------
// Pack recurrent weights into fp16 MFMA B-fragment order (R7-validated).
// ---------------------------------------------------------------------------
__global__ __launch_bounds__(256) void pack_w(
    const float* __restrict__ Wg, const float* __restrict__ Wc, int din,
    _Float16* __restrict__ wpk)
{
  int idx = blockIdx.x * 256 + threadIdx.x;
  if (idx >= 48 * 64) return;
  int tile = idx >> 6, lane = idx & 63;
  int grp = tile >> 4, tt = tile & 15;
  int wv = tt >> 1, s = tt & 1;
  const float* W; int ncols, n0;
  if (grp == 0)      { W = Wg; ncols = 2 * H_; n0 = wv * 32 + s * 16; }
  else if (grp == 1) { W = Wg; ncols = 2 * H_; n0 = 256 + wv * 32 + s * 16; }
  else               { W = Wc; ncols = H_;     n0 = wv * 32 + s * 16; }
  int n = n0 + (lane & 15);
  int kb = (lane >> 4) * 8;
#pragma unroll
  for (int kt = 0; kt < 8; ++kt) {
    _Float16* dst = wpk + ((size_t)(tile * 8 + kt) * 64 + lane) * 8;
#pragma unroll
    for (int j = 0; j < 8; ++j)
      dst[j] = (_Float16)W[(size_t)(din + kt * 32 + kb + j) * ncols + n];
  }
}

// ---------------------------------------------------------------------------
// seqlen[b] = #nonzero ids in row b (valid steps form a prefix).
// ---------------------------------------------------------------------------
__global__ __launch_bounds__(256) void seq_k(const int* __restrict__ ids, int T,
                                             int* __restrict__ seq)
{
  __shared__ int red[256];
  int b = blockIdx.x, tid = threadIdx.x;
  int cnt = 0;
  for (int t = tid; t < T; t += 256) cnt += (ids[b * T + t] != 0) ? 1 : 0;
  red[tid] = cnt;
  __syncthreads();
  for (int s = 128; s > 0; s >>= 1) {
    if (tid < s) red[tid] += red[tid + s];
    __syncthreads();
  }
  if (tid == 0) seq[b] = red[0];
}

// ---------------------------------------------------------------------------
// MFMA input-projection GEMM (R10, unchanged).
// Block 256 thr (4 waves), tile M=64 x N=128, K in 32-ktiles (KT of them).
// Output: fragment-packed G (R9-validated layout, consumed by gru_pers):
//   G[(tl*BATCH + rg*16)*768 + ((ww*6 + 2g+s)*64 + qb*16 + ll)*4 + rb]
// ---------------------------------------------------------------------------
__global__ __launch_bounds__(256) void gemm_mfma(
    const float* __restrict__ Adir, const int* __restrict__ ids,
    const float* __restrict__ emb,
    const _Float16* __restrict__ Bpk, const float* __restrict__ bias,
    float* __restrict__ G, int K, int KT, int t0, int tcsh, int T)
{
  __shared__ __align__(16) _Float16 Al[2][64 * 40];
  __shared__ __align__(16) _Float16 Bl[2][8 * 512];
  const int tid = threadIdx.x;
  const int w = tid >> 6, lane = tid & 63;
  const int quad = lane >> 4, l15 = lane & 15;
  const int m0 = blockIdx.x * 64;
  const int n0 = blockIdx.y * 128;
  const int tc = 1 << tcsh;

  // A-load mapping: row am = tid>>2 (0..63), k-quarter akq = tid&3
  const int am = tid >> 2, akq = tid & 3;
  const int arow = m0 + am;
  const float* asrc;
  if (Adir) {
    asrc = Adir + (size_t)arow * K;
  } else {
    int b = arow >> tcsh, tl = arow & (tc - 1);
    asrc = emb + (size_t)ids[b * T + t0 + tl] * K;
  }

  float a8[8];
  auto loadA = [&](int kt) {
    int k0 = kt * 32 + akq * 8;
#pragma unroll
    for (int j = 0; j < 8; ++j) a8[j] = (k0 + j < K) ? asrc[k0 + j] : 0.f;
  };
  auto writeA = [&](int buf) {
    half8 v;
#pragma unroll
    for (int j = 0; j < 8; ++j) v[j] = (_Float16)a8[j];
    *(half8*)&Al[buf][am * 40 + akq * 8] = v;
  };
  auto stageB = [&](int kt, int buf) {
#pragma unroll
    for (int i = 0; i < 2; ++i) {
      int nt = (n0 >> 4) + w * 2 + i;
      const _Float16* src = Bpk + ((size_t)(kt * 48 + nt) * 64 + lane) * 8;
      __builtin_amdgcn_global_load_lds(
          (const AS1 unsigned int*)src,
          (AS3 unsigned int*)&Bl[buf][(w * 2 + i) * 512 + lane * 8], 16, 0, 0);
    }
  };

  loadA(0);
  stageB(0, 0);
  writeA(0);
  floatx4 acc[4][2] = {};

  for (int kt = 0; kt < KT; ++kt) {
    const int buf = kt & 1;
    __syncthreads();                       // buf fully staged for all waves
    if (kt + 1 < KT) { loadA(kt + 1); stageB(kt + 1, buf ^ 1); }
    half8 bf0 = *(const half8*)&Bl[buf][(w * 2 + 0) * 512 + lane * 8];
    half8 bf1 = *(const half8*)&Bl[buf][(w * 2 + 1) * 512 + lane * 8];
#pragma unroll
    for (int st = 0; st < 4; ++st) {
      half8 af = *(const half8*)&Al[buf][(st * 16 + l15) * 40 + quad * 8];
      acc[st][0] = __builtin_amdgcn_mfma_f32_16x16x32_f16(af, bf0, acc[st][0], 0, 0, 0);
      acc[st][1] = __builtin_amdgcn_mfma_f32_16x16x32_f16(af, bf1, acc[st][1], 0, 0, 0);
    }
    if (kt + 1 < KT) writeA(buf ^ 1);      // buf^1 free: all reads done pre-sync
  }

  // epilogue: bias + fragment-packed G stores
  float bb[2] = { bias[n0 + w * 32 + l15], bias[n0 + w * 32 + 16 + l15] };
#pragma unroll
  for (int s = 0; s < 2; ++s) {
    int col = n0 + w * 32 + s * 16 + l15;
    int g = col >> 8, kk = col & 255;
    int ww = kk >> 5, ss = (kk >> 4) & 1, ll = kk & 15;
    int cc = 2 * g + ss;
#pragma unroll
    for (int st = 0; st < 4; ++st) {
#pragma unroll
      for (int r = 0; r < 4; ++r) {
        int grow = m0 + st * 16 + quad * 4 + r;
        int b = grow >> tcsh, tl = grow & (tc - 1);
        int rg = b >> 4, mm = b & 15, qb = mm >> 2, rb = mm & 3;
        G[((size_t)tl * BATCH + rg * RPB) * NG +
          ((ww * 6 + cc) * 64 + qb * 16 + ll) * 4 + rb] = acc[st][s][r] + bb[s];
      }
    }
  }
}

// ---------------------------------------------------------------------------
// Persistent-weight fused GRU (R9 internals unchanged), generalized to THREE
// uniform job slots so independent streams (body L0, body L1, headline) share
// one dispatch and ride on otherwise-idle CUs. Grid = 24 blocks x 512 thr,
// 1 block/CU; job = blockIdx>>3, row-group = blockIdx&7; null-G jobs exit.
// ---------------------------------------------------------------------------
__global__ __launch_bounds__(512, 1) void gru_pers(
    const float* __restrict__ G0, const _Float16* __restrict__ W0,
    const int* __restrict__ q0, float* __restrict__ o0, float* __restrict__ s0,
    int t00, int tc0,
    const float* __restrict__ G1, const _Float16* __restrict__ W1,
    const int* __restrict__ q1, float* __restrict__ o1, float* __restrict__ s1,
    int t01, int tc1,
    const float* __restrict__ G2, const _Float16* __restrict__ W2,
    const int* __restrict__ q2, float* __restrict__ o2, float* __restrict__ s2,
    int t02, int tc2)
{
  __shared__ __align__(16) _Float16 hpk[4096];    // h frags (fp16)
  __shared__ __align__(16) _Float16 rpk[4096];    // r*h frags (fp16)
  __shared__ __align__(16) float Gs[2][12288];    // staged G, wave-private

  const int job = blockIdx.x >> 3, rg = blockIdx.x & 7;
  const float* G; const _Float16* Wsrc; const int* seq;
  float* outp; float* state; int t0, tcl;
  if (job == 0)      { G = G0; Wsrc = W0; seq = q0; outp = o0; state = s0; t0 = t00; tcl = tc0; }
  else if (job == 1) { G = G1; Wsrc = W1; seq = q1; outp = o1; state = s1; t0 = t01; tcl = tc1; }
  else               { G = G2; Wsrc = W2; seq = q2; outp = o2; state = s2; t0 = t02; tcl = tc2; }
  if (!G) return;

  const int tid = threadIdx.x;
  const int w = tid >> 6, lane = tid & 63;
  const int quad = lane >> 4, l15 = lane & 15;

  // --- load weights once; pin (blocks rematerialization/sinking) ----------
  floatx4 wg[4][8];   // gate tiles -> VGPRs
  floatx4 wc[2][8];   // candidate tiles -> AGPRs
#pragma unroll
  for (int i = 0; i < 4; ++i) {
    const int tile = (i >> 1) * 16 + w * 2 + (i & 1);
#pragma unroll
    for (int kt = 0; kt < 8; ++kt) {
      wg[i][kt] = *(const floatx4*)&Wsrc[((size_t)(tile * 8 + kt) * 64 + lane) * 8];
      asm volatile("" : "+v"(wg[i][kt]));
    }
  }
#pragma unroll
  for (int i = 0; i < 2; ++i) {
    const int tile = 32 + w * 2 + i;
#pragma unroll
    for (int kt = 0; kt < 8; ++kt) {
      wc[i][kt] = *(const floatx4*)&Wsrc[((size_t)(tile * 8 + kt) * 64 + lane) * 8];
      asm volatile("" : "+a"(wc[i][kt]));
    }
  }

  // --- seq / steps ---------------------------------------------------------
  int seq4[4];
#pragma unroll
  for (int r = 0; r < 4; ++r) seq4[r] = seq[rg * RPB + quad * 4 + r];
  int Smax = 0;
#pragma unroll
  for (int i = 0; i < 16; ++i) Smax = max(Smax, seq[rg * RPB + i]);
  int steps = Smax - t0;
  if (steps < 0) steps = 0;
  if (steps > tcl) steps = tcl;

  // --- frag addressing (R7-validated bank-exact layout) --------------------
  const int wbase = (w * 64 + quad * 2 + (l15 >> 3)) * 8 + (l15 & 7);
  const int rbase = (((quad >> 1) << 5) + ((l15 & 3) << 3) +
                     ((l15 >> 2) << 1) + (quad & 1)) * 8;

  // --- h_reg init + h frag fill -------------------------------------------
  float h_reg[2][4];
#pragma unroll
  for (int s = 0; s < 2; ++s)
#pragma unroll
    for (int r = 0; r < 4; ++r) {
      int row = quad * 4 + r, k = w * 32 + s * 16 + l15;
      float v = (t0 == 0) ? 0.f : state[(size_t)(rg * RPB + row) * H_ + k];
      h_reg[s][r] = v;
      hpk[wbase + s * 256 + r * 64] = (_Float16)v;
    }

  // --- async G staging: wave w copies its own 6 chunks (1 KB each) --------
  const float* gblk = G + (size_t)rg * RPB * NG + w * (6 * 256);
  float* ldsw = &Gs[0][0] + w * (6 * 256);
  auto stage = [&](int t, int buf) {
    const float* gp = gblk + (size_t)t * BATCH * NG;
    float* lp = ldsw + buf * 12288;
#pragma unroll
    for (int c = 0; c < 6; ++c) {
      __builtin_amdgcn_global_load_lds(
          (const AS1 unsigned int*)(gp + c * 256 + lane * 4),
          (AS3 unsigned int*)(lp + c * 256), 16, 0, 0);
    }
  };
  if (steps > 0) stage(0, 0);
  __syncthreads();   // one full drain: loads for t=0 complete + hpk visible

  const _Float16* hA = &hpk[rbase];
  const _Float16* rA = &rpk[rbase];

  for (int t = 0; t < steps; ++t) {
    const int buf = t & 1;
    const bool staged = (t + 1 < steps);
    if (staged) stage(t + 1, buf ^ 1);   // async prefetch next step's G

    // ---------------- phase A: 4 gate tiles (r s=0,1 ; u s=0,1) ----------
    floatx4 acc[4] = {};
#pragma unroll
    for (int kt = 0; kt < 8; ++kt) {
      half8 a = *(const half8*)&hA[kt * 512];
#pragma unroll
      for (int s = 0; s < 4; ++s)
        acc[s] = __builtin_amdgcn_mfma_f32_16x16x32_f16(
            a, __builtin_bit_cast(half8, wg[s][kt]), acc[s], 0, 0, 0);
    }

    if (staged) {
      if (outp) __builtin_amdgcn_s_waitcnt(WC_VM14);
      else      __builtin_amdgcn_s_waitcnt(WC_VM6);
    } else {
      __builtin_amdgcn_s_waitcnt(WC_VM0);
    }

    floatx4 gA[4];
#pragma unroll
    for (int c = 0; c < 4; ++c)
      gA[c] = *(const floatx4*)&Gs[buf][(w * 6 + c) * 256 + lane * 4];

#pragma unroll
    for (int s = 0; s < 2; ++s)
#pragma unroll
      for (int r = 0; r < 4; ++r) {
        float pre = acc[s][r] + gA[s][r];
        float g = __builtin_amdgcn_rcpf(1.f + __expf(-pre));
        rpk[wbase + s * 256 + r * 64] = (_Float16)(g * h_reg[s][r]);
      }
    float u_reg[2][4];
#pragma unroll
    for (int s = 0; s < 2; ++s)
#pragma unroll
      for (int r = 0; r < 4; ++r) {
        float pre = acc[2 + s][r] + gA[2 + s][r];
        u_reg[s][r] = __builtin_amdgcn_rcpf(1.f + __expf(-pre));
      }
    __builtin_amdgcn_s_waitcnt(WC_LGKM0);   // rpk visible
    __builtin_amdgcn_s_barrier();

    // ---------------- phase B: 2 candidate tiles --------------------------
    floatx4 accB[2] = {};
#pragma unroll
    for (int kt = 0; kt < 8; ++kt) {
      half8 a = *(const half8*)&rA[kt * 512];
#pragma unroll
      for (int s = 0; s < 2; ++s)
        accB[s] = __builtin_amdgcn_mfma_f32_16x16x32_f16(
            a, __builtin_bit_cast(half8, wc[s][kt]), accB[s], 0, 0, 0);
    }
    floatx4 gB[2];
#pragma unroll
    for (int s = 0; s < 2; ++s)
      gB[s] = *(const floatx4*)&Gs[buf][(w * 6 + 4 + s) * 256 + lane * 4];

#pragma unroll
    for (int s = 0; s < 2; ++s)
#pragma unroll
      for (int r = 0; r < 4; ++r) {
        int row = quad * 4 + r;
        float pre = accB[s][r] + gB[s][r];
        float c = 1.f - 2.f * __builtin_amdgcn_rcpf(1.f + __expf(2.f * pre));
        float u = u_reg[s][r];
        float hn = u * h_reg[s][r] + (1.f - u) * c;
        bool valid = (t0 + t) < seq4[r];
        hn = valid ? hn : h_reg[s][r];
        h_reg[s][r] = hn;
        hpk[wbase + s * 256 + r * 64] = (_Float16)hn;
        if (outp)
          outp[((size_t)(rg * RPB + row) * tcl + t) * H_ + (w * 32 + s * 16 + l15)] =
              valid ? hn : 0.f;
      }
    __builtin_amdgcn_s_waitcnt(WC_LGKM0);   // hpk visible
    __builtin_amdgcn_s_barrier();
  }
  // --- save state from fp32 masters ---------------------------------------
#pragma unroll
  for (int s = 0; s < 2; ++s)
#pragma unroll
    for (int r = 0; r < 4; ++r)
      state[(size_t)(rg * RPB + quad * 4 + r) * H_ + (w * 32 + s * 16 + l15)] =
          h_reg[s][r];
}

// ---------------------------------------------------------------------------
// Final prediction: out[b, c] = [h_head | h_body] @ W_pred + b_pred.
// ---------------------------------------------------------------------------
__global__ __launch_bounds__(512) void pred_k(
    const float* __restrict__ hh, const float* __restrict__ hb,
    const float* __restrict__ Wp, const float* __restrict__ bpred,
    float* __restrict__ out)
{
  int tid = threadIdx.x;
  int b = tid >> 2, c = tid & 3;
  float acc = bpred[c];
  for (int k = 0; k < H_; ++k) acc += hh[b * H_ + k] * Wp[k * 4 + c];
  for (int k = 0; k < H_; ++k) acc += hb[b * H_ + k] * Wp[(H_ + k) * 4 + c];
  out[b * 4 + c] = acc;
}

// ---------------------------------------------------------------------------
extern "C" void kernel_launch(void* const* d_in, const int* in_sizes, int n_in,
                              void* d_out, int out_size, void* d_ws, size_t ws_size,
                              hipStream_t stream)
{
  (void)in_sizes; (void)n_in; (void)out_size;
  const int*   idsH = (const int*)  d_in[0];
  const int*   idsB = (const int*)  d_in[1];
  const float* emb  = (const float*)d_in[2];
  const float* Wp   = (const float*)d_in[3];
  const float* bp   = (const float*)d_in[4];
  const float* W[4][4];   // [hd0,hd1,bd0,bd1][Wg,bg,Wc,bc]
  for (int s = 0; s < 4; ++s)
    for (int q = 0; q < 4; ++q)
      W[s][q] = (const float*)d_in[5 + s * 4 + q];

  // choose time-chunk CH to fit ws_size; merged-head schedule needs extra
  // GH1+OcH+stH0 (~4.3M floats) and CH >= TH_. Fall back to the serial
  // per-stream schedule if that doesn't fit (never worse than baseline).
  const size_t fixed_merged = 6000000;
  const size_t fixed_plain  = 1600000;
  int CH = 64;
  bool merged = true;
  while (CH > 8 && (fixed_merged + (size_t)BATCH * CH * (2 * NG + H_)) * 4 > ws_size)
    CH >>= 1;
  if (CH < TH_) {
    merged = false;
    CH = 64;
    while (CH > 8 && (fixed_plain + (size_t)BATCH * CH * (2 * NG + H_)) * 4 > ws_size)
      CH >>= 1;
  }
  const int CHH = (CH < TH_) ? CH : TH_;
  const int tcshB = __builtin_ctz(CH), tcshH = __builtin_ctz(CHH);

  float* wbase = (float*)d_ws;
  size_t off = 0;
  auto alloc = [&](size_t n) {
    float* p = wbase + off; off += (n + 255) & ~(size_t)255; return p;
  };
  int* seqH = (int*)alloc(BATCH);
  int* seqB = (int*)alloc(BATCH);
  float* bi[4]; _Float16* Wpk[4]; _Float16* Bxh[4];
  const int din[4] = {E_, H_, E_, H_};
  const int KT[4]  = {10, 8, 10, 8};        // ceil(din/32)
  for (int s = 0; s < 4; ++s) {
    bi[s]  = alloc(NG);
    Wpk[s] = (_Float16*)alloc(48 * 8 * 64 * 8 / 2);       // 384 KB fp16
    Bxh[s] = (_Float16*)alloc((size_t)10 * 48 * 64 * 8 / 2); // ≤480 KB fp16
  }
  float* st0 = alloc((size_t)BATCH * H_);   // body layer-0 carry
  float* stH0 = alloc((size_t)BATCH * H_);  // head layer-0 carry (merged)
  float* hfH = alloc((size_t)BATCH * H_);   // head layer-1 carry/final
  float* hfB = alloc((size_t)BATCH * H_);   // body layer-1 carry/final
  float* Gc0 = alloc((size_t)BATCH * CH * NG);
  float* Gc1 = alloc((size_t)BATCH * CH * NG);
  float* Oc  = alloc((size_t)BATCH * CH * H_);
  // merged-head extras (touched only on the merged path)
  float* GH1 = alloc((size_t)BATCH * TH_ * NG);
  float* OcH = alloc((size_t)BATCH * TH_ * H_);
  float* GH0 = Gc1;   // alias: Gc1 is unused until gemm_L1(c0), which runs later

  // 1. pack weights
  for (int s = 0; s < 4; ++s) {
    pack_bias<<<(NG + 255) / 256, 256, 0, stream>>>(W[s][1], W[s][3], bi[s]);
    pack_w<<<(48 * 64 + 255) / 256, 256, 0, stream>>>(
        W[s][0], W[s][2], din[s], Wpk[s]);
    pack_bx<<<(KT[s] * 48 * 64 + 255) / 256, 256, 0, stream>>>(
        W[s][0], W[s][2], din[s], KT[s], Bxh[s]);
  }
  // 2. seqlens
  seq_k<<<BATCH, 256, 0, stream>>>(idsH, TH_, seqH);
  seq_k<<<BATCH, 256, 0, stream>>>(idsB, TB_, seqB);

  auto gru3 = [&](const float* g0, const _Float16* w0, const int* x0, float* y0,
                  float* z0, int a0, int b0,
                  const float* g1, const _Float16* w1, const int* x1, float* y1,
                  float* z1, int a1, int b1,
                  const float* g2, const _Float16* w2, const int* x2, float* y2,
                  float* z2, int a2, int b2) {
    gru_pers<<<3 * NBLK, 512, 0, stream>>>(g0, w0, x0, y0, z0, a0, b0,
                                           g1, w1, x1, y1, z1, a1, b1,
                                           g2, w2, x2, y2, z2, a2, b2);
  };

  if (merged) {
    // 3a. headline rides as job-2 inside the first two body dispatches.
    dim3 ggH(BATCH * TH_ / 64, NG / 128);
    gemm_mfma<<<ggH, 256, 0, stream>>>(nullptr, idsH, emb, Bxh[0], bi[0],
                                       GH0, E_, KT[0], 0, 5, TH_);
    const int nch = TB_ / CH;
    dim3 gg(BATCH * CH / 64, NG / 128);
    for (int c = 0; c < nch; ++c) {
      int t0 = c * CH;
      gemm_mfma<<<gg, 256, 0, stream>>>(nullptr, idsB, emb, Bxh[2], bi[2],
                                        Gc0, E_, KT[2], t0, tcshB, TB_);
      const float* g2 = (c == 0) ? GH0 : (c == 1) ? GH1 : nullptr;
      gru3(Gc0, Wpk[2], seqB, Oc, st0, t0, CH,
           (c > 0) ? Gc1 : nullptr, Wpk[3], seqB, nullptr, hfB, (c - 1) * CH, CH,
           g2, Wpk[(c == 0) ? 0 : 1], seqH,
           (c == 0) ? OcH : nullptr, (c == 0) ? stH0 : hfH, 0, TH_);
      if (c == 0)
        gemm_mfma<<<ggH, 256, 0, stream>>>(OcH, nullptr, nullptr, Bxh[1], bi[1],
                                           GH1, H_, KT[1], 0, 5, TH_);
      gemm_mfma<<<gg, 256, 0, stream>>>(Oc, nullptr, nullptr, Bxh[3], bi[3],
                                        Gc1, H_, KT[3], 0, tcshB, TB_);
    }
    // drain: last body layer-1 chunk
    gru3(nullptr, Wpk[2], seqB, nullptr, st0, 0, CH,
         Gc1, Wpk[3], seqB, nullptr, hfB, (nch - 1) * CH, CH,
         nullptr, Wpk[1], seqH, nullptr, hfH, 0, TH_);
  } else {
    // 3b. fallback: serial per-stream chunk pipeline (baseline schedule)
    auto run_stream = [&](const int* ids, int T, int chs, int tcsh,
                          const int* seq, int l0, int l1, float* hf) {
      int nchunks = T / chs;
      dim3 gg(BATCH * chs / 64, NG / 128);
      for (int c = 0; c < nchunks; ++c) {
        int t0 = c * chs;
        gemm_mfma<<<gg, 256, 0, stream>>>(nullptr, ids, emb, Bxh[l0], bi[l0],
                                          Gc0, E_, KT[l0], t0, tcsh, T);
        gru3(Gc0, Wpk[l0], seq, Oc, st0, t0, chs,
             (c > 0) ? Gc1 : nullptr, Wpk[l1], seq, nullptr, hf, (c - 1) * chs, chs,
             nullptr, Wpk[l1], seq, nullptr, hf, 0, chs);
        gemm_mfma<<<gg, 256, 0, stream>>>(Oc, nullptr, nullptr, Bxh[l1], bi[l1],
                                          Gc1, H_, KT[l1], 0, tcsh, T);
      }
      gru3(nullptr, Wpk[l0], seq, nullptr, st0, 0, chs,
           Gc1, Wpk[l1], seq, nullptr, hf, (nchunks - 1) * chs, chs,
           nullptr, Wpk[l1], seq, nullptr, hf, 0, chs);
    };
    run_stream(idsH, TH_, CHH, tcshH, seqH, 0, 1, hfH);   // headline
    run_stream(idsB, TB_, CH,  tcshB, seqB, 2, 3, hfB);   // body
  }

  // 4. prediction head
  pred_k<<<1, 512, 0, stream>>>(hfH, hfB, Wp, bp, (float*)d_out);
}

// Round 2
// 2570.522 us; speedup vs baseline: 1.2436x; 1.1360x over previous
//
#include <hip/hip_runtime.h>
#include <cstdint>
#include <cstddef>

// Problem constants: V=50000, E=300, NF=1, H=256, B=128, TH=32, TB=512, NC=4.
#define H_    256
#define NG    768      // 512 gate cols (r|u) + 256 candidate cols, packed
#define BATCH 128
#define TH_   32
#define TB_   512
#define E_    300
#define RPB   16             // batch rows per gru block
#define NBLK  (BATCH / RPB)  // 8 row-groups per job; gru portion = 24 blocks (3 jobs)

typedef _Float16 half8 __attribute__((ext_vector_type(8)));
typedef float    floatx4 __attribute__((ext_vector_type(4)));

#define AS1 __attribute__((address_space(1)))
#define AS3 __attribute__((address_space(3)))

// s_waitcnt immediates (gfx9 encoding: vmcnt[3:0]=imm[3:0], vmcnt[5:4]=imm[15:14],
// expcnt=imm[6:4], lgkmcnt=imm[11:8]).
#define WC_LGKM0 0xC07F   // lgkmcnt(0), vmcnt/exp unconstrained
#define WC_VM14  0x0F7E   // vmcnt(14) only
#define WC_VM6   0x0F76   // vmcnt(6)  only
#define WC_VM0   0x0F70   // vmcnt(0)  only

// ---------------------------------------------------------------------------
// bias[j] = [bg | bc] (768)
// ---------------------------------------------------------------------------
__global__ __launch_bounds__(256) void pack_bias(
    const float* __restrict__ bg, const float* __restrict__ bc,
    float* __restrict__ bias)
{
  int idx = blockIdx.x * 256 + threadIdx.x;
  if (idx < NG) bias[idx] = (idx < 2 * H_) ? bg[idx] : bc[idx - 2 * H_];
}

// ---------------------------------------------------------------------------
// Pack INPUT-projection weights into fp16 MFMA B-frag tiles for gemm_mfma.
// Global layout [kt][nt][lane][8]: tile (nt 0..47, kt 0..KT-1) holds
// B[k = kt*32 + (l>>4)*8 + j][col = nt*16 + (l&15)], zero-padded k>=din.
// col<512 -> Wg, else Wc col-512.
// ---------------------------------------------------------------------------
__global__ __launch_bounds__(256) void pack_bx(
    const float* __restrict__ Wg, const float* __restrict__ Wc,
    int din, int KT, _Float16* __restrict__ out)
{
  int idx = blockIdx.x * 256 + threadIdx.x;
  if (idx >= KT * 48 * 64) return;
  int lane = idx & 63, tile = idx >> 6;
  int kt = tile / 48, nt = tile - kt * 48;
  int col = nt * 16 + (lane & 15);
  int k0 = kt * 32 + (lane >> 4) * 8;
  const float* W; int ncols, c2;
  if (col < 2 * H_) { W = Wg; ncols = 2 * H_; c2 = col; }
  else              { W = Wc; ncols = H_;     c2 = col - 2 * H_; }
  _Float16* dst = out + ((size_t)(kt * 48 + nt) * 64 + lane) * 8;
#pragma unroll
  for (int j = 0; j < 8; ++j) {
    int k = k0 + j;
    dst[j] = (k < din) ? (_Float16)W[(size_t)k * ncols + c2] : (_Float16)0.f;
  }
}

// ---------------------------------------------------------------------------
// Pack recurrent weights into fp16 MFMA B-fragment order (R7-validated).
// ---------------------------------------------------------------------------
__global__ __launch_bounds__(256) void pack_w(
    const float* __restrict__ Wg, const float* __restrict__ Wc, int din,
    _Float16* __restrict__ wpk)
{
  int idx = blockIdx.x * 256 + threadIdx.x;
  if (idx >= 48 * 64) return;
  int tile = idx >> 6, lane = idx & 63;
  int grp = tile >> 4, tt = tile & 15;
  int wv = tt >> 1, s = tt & 1;
  const float* W; int ncols, n0;
  if (grp == 0)      { W = Wg; ncols = 2 * H_; n0 = wv * 32 + s * 16; }
  else if (grp == 1) { W = Wg; ncols = 2 * H_; n0 = 256 + wv * 32 + s * 16; }
  else               { W = Wc; ncols = H_;     n0 = wv * 32 + s * 16; }
  int n = n0 + (lane & 15);
  int kb = (lane >> 4) * 8;
#pragma unroll
  for (int kt = 0; kt < 8; ++kt) {
    _Float16* dst = wpk + ((size_t)(tile * 8 + kt) * 64 + lane) * 8;
#pragma unroll
    for (int j = 0; j < 8; ++j)
      dst[j] = (_Float16)W[(size_t)(din + kt * 32 + kb + j) * ncols + n];
  }
}

// ---------------------------------------------------------------------------
// seqlen[b] = #nonzero ids in row b (valid steps form a prefix).
// ---------------------------------------------------------------------------
__global__ __launch_bounds__(256) void seq_k(const int* __restrict__ ids, int T,
                                             int* __restrict__ seq)
{
  __shared__ int red[256];
  int b = blockIdx.x, tid = threadIdx.x;
  int cnt = 0;
  for (int t = tid; t < T; t += 256) cnt += (ids[b * T + t] != 0) ? 1 : 0;
  red[tid] = cnt;
  __syncthreads();
  for (int s = 128; s > 0; s >>= 1) {
    if (tid < s) red[tid] += red[tid + s];
    __syncthreads();
  }
  if (tid == 0) seq[b] = red[0];
}

// ---------------------------------------------------------------------------
// MFMA input-projection GEMM (R10, unchanged). Standalone version.
// Block 256 thr (4 waves), tile M=64 x N=128, K in 32-ktiles (KT of them).
// Output: fragment-packed G (R9-validated layout, consumed by gru_pers).
// ---------------------------------------------------------------------------
__global__ __launch_bounds__(256) void gemm_mfma(
    const float* __restrict__ Adir, const int* __restrict__ ids,
    const float* __restrict__ emb,
    const _Float16* __restrict__ Bpk, const float* __restrict__ bias,
    float* __restrict__ G, int K, int KT, int t0, int tcsh, int T)
{
  __shared__ __align__(16) _Float16 Al[2][64 * 40];
  __shared__ __align__(16) _Float16 Bl[2][8 * 512];
  const int tid = threadIdx.x;
  const int w = tid >> 6, lane = tid & 63;
  const int quad = lane >> 4, l15 = lane & 15;
  const int m0 = blockIdx.x * 64;
  const int n0 = blockIdx.y * 128;
  const int tc = 1 << tcsh;

  const int am = tid >> 2, akq = tid & 3;
  const int arow = m0 + am;
  const float* asrc;
  if (Adir) {
    asrc = Adir + (size_t)arow * K;
  } else {
    int b = arow >> tcsh, tl = arow & (tc - 1);
    asrc = emb + (size_t)ids[b * T + t0 + tl] * K;
  }

  float a8[8];
  auto loadA = [&](int kt) {
    int k0 = kt * 32 + akq * 8;
#pragma unroll
    for (int j = 0; j < 8; ++j) a8[j] = (k0 + j < K) ? asrc[k0 + j] : 0.f;
  };
  auto writeA = [&](int buf) {
    half8 v;
#pragma unroll
    for (int j = 0; j < 8; ++j) v[j] = (_Float16)a8[j];
    *(half8*)&Al[buf][am * 40 + akq * 8] = v;
  };
  auto stageB = [&](int kt, int buf) {
#pragma unroll
    for (int i = 0; i < 2; ++i) {
      int nt = (n0 >> 4) + w * 2 + i;
      const _Float16* src = Bpk + ((size_t)(kt * 48 + nt) * 64 + lane) * 8;
      __builtin_amdgcn_global_load_lds(
          (const AS1 unsigned int*)src,
          (AS3 unsigned int*)&Bl[buf][(w * 2 + i) * 512 + lane * 8], 16, 0, 0);
    }
  };

  loadA(0);
  stageB(0, 0);
  writeA(0);
  floatx4 acc[4][2] = {};

  for (int kt = 0; kt < KT; ++kt) {
    const int buf = kt & 1;
    __syncthreads();
    if (kt + 1 < KT) { loadA(kt + 1); stageB(kt + 1, buf ^ 1); }
    half8 bf0 = *(const half8*)&Bl[buf][(w * 2 + 0) * 512 + lane * 8];
    half8 bf1 = *(const half8*)&Bl[buf][(w * 2 + 1) * 512 + lane * 8];
#pragma unroll
    for (int st = 0; st < 4; ++st) {
      half8 af = *(const half8*)&Al[buf][(st * 16 + l15) * 40 + quad * 8];
      acc[st][0] = __builtin_amdgcn_mfma_f32_16x16x32_f16(af, bf0, acc[st][0], 0, 0, 0);
      acc[st][1] = __builtin_amdgcn_mfma_f32_16x16x32_f16(af, bf1, acc[st][1], 0, 0, 0);
    }
    if (kt + 1 < KT) writeA(buf ^ 1);
  }

  float bb[2] = { bias[n0 + w * 32 + l15], bias[n0 + w * 32 + 16 + l15] };
#pragma unroll
  for (int s = 0; s < 2; ++s) {
    int col = n0 + w * 32 + s * 16 + l15;
    int g = col >> 8, kk = col & 255;
    int ww = kk >> 5, ss = (kk >> 4) & 1, ll = kk & 15;
    int cc = 2 * g + ss;
#pragma unroll
    for (int st = 0; st < 4; ++st) {
#pragma unroll
      for (int r = 0; r < 4; ++r) {
        int grow = m0 + st * 16 + quad * 4 + r;
        int b = grow >> tcsh, tl = grow & (tc - 1);
        int rg = b >> 4, mm = b & 15, qb = mm >> 2, rb = mm & 3;
        G[((size_t)tl * BATCH + rg * RPB) * NG +
          ((ww * 6 + cc) * 64 + qb * 16 + ll) * 4 + rb] = acc[st][s][r] + bb[s];
      }
    }
  }
}

// ---------------------------------------------------------------------------
// Persistent-weight fused GRU (R9 internals unchanged) with THREE job slots
// (body L0, body L1, headline) + GEMM RIDER blocks: blocks >= 3*NBLK each
// compute two independent M64xN128 input-projection tiles for the NEXT
// chunk's body-L0 G (fully independent of the gru jobs; double-buffered
// destination). Riders hide under the 243us gru critical path on idle CUs.
// gru blocks are ids 0..23 (within the first CU fill wave -> resident at t0).
// ---------------------------------------------------------------------------
__global__ __launch_bounds__(512, 1) void gru_pers(
    const float* __restrict__ G0, const _Float16* __restrict__ W0,
    const int* __restrict__ q0, float* __restrict__ o0, float* __restrict__ s0,
    int t00, int tc0,
    const float* __restrict__ G1, const _Float16* __restrict__ W1,
    const int* __restrict__ q1, float* __restrict__ o1, float* __restrict__ s1,
    int t01, int tc1,
    const float* __restrict__ G2, const _Float16* __restrict__ W2,
    const int* __restrict__ q2, float* __restrict__ o2, float* __restrict__ s2,
    int t02, int tc2,
    const int* __restrict__ g_ids, const float* __restrict__ g_emb,
    const _Float16* __restrict__ g_Bpk, const float* __restrict__ g_bias,
    float* __restrict__ g_G, int g_KT, int g_t0, int g_tcsh, int g_T, int g_nbx)
{
  __shared__ __align__(16) char smem[114688];

  const int tid = threadIdx.x;

  if (blockIdx.x >= 3 * NBLK) {
    // ================= GEMM RIDER: two tiles per 512-thr block ============
    // half 0 = waves 0-3, half 1 = waves 4-7; identical KT loop => the
    // block-wide __syncthreads() are phase-aligned across halves.
    const int half = tid >> 8;
    _Float16* Al = (_Float16*)(smem + half * 10240);           // [2][2560]
    _Float16* Bl = (_Float16*)(smem + 20480 + half * 16384);   // [2][4096]
    const int t256 = tid & 255;
    const int w4 = (tid >> 6) & 3, lane = tid & 63;
    const int quad = lane >> 4, l15 = lane & 15;
    const int tidx = (blockIdx.x - 3 * NBLK) * 2 + half;
    const int bx = tidx % g_nbx, by = tidx / g_nbx;
    const int m0 = bx * 64, n0 = by * 128;
    const int tc = 1 << g_tcsh;

    const int am = t256 >> 2, akq = t256 & 3;
    const int arow = m0 + am;
    const int ab = arow >> g_tcsh, atl = arow & (tc - 1);
    const float* asrc = g_emb + (size_t)g_ids[ab * g_T + g_t0 + atl] * E_;

    float a8[8];
    auto loadA = [&](int kt) {
      int k0 = kt * 32 + akq * 8;
#pragma unroll
      for (int j = 0; j < 8; ++j) a8[j] = (k0 + j < E_) ? asrc[k0 + j] : 0.f;
    };
    auto writeA = [&](int buf) {
      half8 v;
#pragma unroll
      for (int j = 0; j < 8; ++j) v[j] = (_Float16)a8[j];
      *(half8*)&Al[buf * 2560 + am * 40 + akq * 8] = v;
    };
    auto stageB = [&](int kt, int buf) {
#pragma unroll
      for (int i = 0; i < 2; ++i) {
        int nt = (n0 >> 4) + w4 * 2 + i;
        const _Float16* src = g_Bpk + ((size_t)(kt * 48 + nt) * 64 + lane) * 8;
        __builtin_amdgcn_global_load_lds(
            (const AS1 unsigned int*)src,
            (AS3 unsigned int*)&Bl[buf * 4096 + (w4 * 2 + i) * 512 + lane * 8],
            16, 0, 0);
      }
    };

    loadA(0);
    stageB(0, 0);
    writeA(0);
    floatx4 acc[4][2] = {};

    for (int kt = 0; kt < g_KT; ++kt) {
      const int buf = kt & 1;
      __syncthreads();
      if (kt + 1 < g_KT) { loadA(kt + 1); stageB(kt + 1, buf ^ 1); }
      half8 bf0 = *(const half8*)&Bl[buf * 4096 + (w4 * 2 + 0) * 512 + lane * 8];
      half8 bf1 = *(const half8*)&Bl[buf * 4096 + (w4 * 2 + 1) * 512 + lane * 8];
#pragma unroll
      for (int st = 0; st < 4; ++st) {
        half8 af = *(const half8*)&Al[buf * 2560 + (st * 16 + l15) * 40 + quad * 8];
        acc[st][0] = __builtin_amdgcn_mfma_f32_16x16x32_f16(af, bf0, acc[st][0], 0, 0, 0);
        acc[st][1] = __builtin_amdgcn_mfma_f32_16x16x32_f16(af, bf1, acc[st][1], 0, 0, 0);
      }
      if (kt + 1 < g_KT) writeA(buf ^ 1);
    }

    float bb[2] = { g_bias[n0 + w4 * 32 + l15], g_bias[n0 + w4 * 32 + 16 + l15] };
#pragma unroll
    for (int s = 0; s < 2; ++s) {
      int col = n0 + w4 * 32 + s * 16 + l15;
      int g = col >> 8, kk = col & 255;
      int ww = kk >> 5, ss = (kk >> 4) & 1, ll = kk & 15;
      int cc = 2 * g + ss;
#pragma unroll
      for (int st = 0; st < 4; ++st) {
#pragma unroll
        for (int r = 0; r < 4; ++r) {
          int grow = m0 + st * 16 + quad * 4 + r;
          int b = grow >> g_tcsh, tl = grow & (tc - 1);
          int rg2 = b >> 4, mm = b & 15, qb = mm >> 2, rb = mm & 3;
          g_G[((size_t)tl * BATCH + rg2 * RPB) * NG +
              ((ww * 6 + cc) * 64 + qb * 16 + ll) * 4 + rb] = acc[st][s][r] + bb[s];
        }
      }
    }
    return;
  }

  // ===================== GRU path (R9 internals unchanged) ================
  _Float16* hpk = (_Float16*)smem;              // 4096 halves
  _Float16* rpk = (_Float16*)(smem + 8192);     // 4096 halves
  float* GsB = (float*)(smem + 16384);          // [2][12288] floats

  const int job = blockIdx.x >> 3, rg = blockIdx.x & 7;
  const float* G; const _Float16* Wsrc; const int* seq;
  float* outp; float* state; int t0, tcl;
  if (job == 0)      { G = G0; Wsrc = W0; seq = q0; outp = o0; state = s0; t0 = t00; tcl = tc0; }
  else if (job == 1) { G = G1; Wsrc = W1; seq = q1; outp = o1; state = s1; t0 = t01; tcl = tc1; }
  else               { G = G2; Wsrc = W2; seq = q2; outp = o2; state = s2; t0 = t02; tcl = tc2; }
  if (!G) return;

  const int w = tid >> 6, lane = tid & 63;
  const int quad = lane >> 4, l15 = lane & 15;

  // --- load weights once; pin (blocks rematerialization/sinking) ----------
  floatx4 wg[4][8];   // gate tiles -> VGPRs
  floatx4 wc[2][8];   // candidate tiles -> AGPRs
#pragma unroll
  for (int i = 0; i < 4; ++i) {
    const int tile = (i >> 1) * 16 + w * 2 + (i & 1);
#pragma unroll
    for (int kt = 0; kt < 8; ++kt) {
      wg[i][kt] = *(const floatx4*)&Wsrc[((size_t)(tile * 8 + kt) * 64 + lane) * 8];
      asm volatile("" : "+v"(wg[i][kt]));
    }
  }
#pragma unroll
  for (int i = 0; i < 2; ++i) {
    const int tile = 32 + w * 2 + i;
#pragma unroll
    for (int kt = 0; kt < 8; ++kt) {
      wc[i][kt] = *(const floatx4*)&Wsrc[((size_t)(tile * 8 + kt) * 64 + lane) * 8];
      asm volatile("" : "+a"(wc[i][kt]));
    }
  }

  // --- seq / steps ---------------------------------------------------------
  int seq4[4];
#pragma unroll
  for (int r = 0; r < 4; ++r) seq4[r] = seq[rg * RPB + quad * 4 + r];
  int Smax = 0;
#pragma unroll
  for (int i = 0; i < 16; ++i) Smax = max(Smax, seq[rg * RPB + i]);
  int steps = Smax - t0;
  if (steps < 0) steps = 0;
  if (steps > tcl) steps = tcl;

  // --- frag addressing (R7-validated bank-exact layout) --------------------
  const int wbase = (w * 64 + quad * 2 + (l15 >> 3)) * 8 + (l15 & 7);
  const int rbase = (((quad >> 1) << 5) + ((l15 & 3) << 3) +
                     ((l15 >> 2) << 1) + (quad & 1)) * 8;

  // --- h_reg init + h frag fill -------------------------------------------
  float h_reg[2][4];
#pragma unroll
  for (int s = 0; s < 2; ++s)
#pragma unroll
    for (int r = 0; r < 4; ++r) {
      int row = quad * 4 + r, k = w * 32 + s * 16 + l15;
      float v = (t0 == 0) ? 0.f : state[(size_t)(rg * RPB + row) * H_ + k];
      h_reg[s][r] = v;
      hpk[wbase + s * 256 + r * 64] = (_Float16)v;
    }

  // --- async G staging: wave w copies its own 6 chunks (1 KB each) --------
  const float* gblk = G + (size_t)rg * RPB * NG + w * (6 * 256);
  float* ldsw = GsB + w * (6 * 256);
  auto stage = [&](int t, int buf) {
    const float* gp = gblk + (size_t)t * BATCH * NG;
    float* lp = ldsw + buf * 12288;
#pragma unroll
    for (int c = 0; c < 6; ++c) {
      __builtin_amdgcn_global_load_lds(
          (const AS1 unsigned int*)(gp + c * 256 + lane * 4),
          (AS3 unsigned int*)(lp + c * 256), 16, 0, 0);
    }
  };
  if (steps > 0) stage(0, 0);
  __syncthreads();   // one full drain: loads for t=0 complete + hpk visible

  const _Float16* hA = &hpk[rbase];
  const _Float16* rA = &rpk[rbase];

  for (int t = 0; t < steps; ++t) {
    const int buf = t & 1;
    const bool staged = (t + 1 < steps);
    if (staged) stage(t + 1, buf ^ 1);   // async prefetch next step's G

    // ---------------- phase A: 4 gate tiles (r s=0,1 ; u s=0,1) ----------
    floatx4 acc[4] = {};
#pragma unroll
    for (int kt = 0; kt < 8; ++kt) {
      half8 a = *(const half8*)&hA[kt * 512];
#pragma unroll
      for (int s = 0; s < 4; ++s)
        acc[s] = __builtin_amdgcn_mfma_f32_16x16x32_f16(
            a, __builtin_bit_cast(half8, wg[s][kt]), acc[s], 0, 0, 0);
    }

    if (staged) {
      if (outp) __builtin_amdgcn_s_waitcnt(WC_VM14);
      else      __builtin_amdgcn_s_waitcnt(WC_VM6);
    } else {
      __builtin_amdgcn_s_waitcnt(WC_VM0);
    }

    floatx4 gA[4];
#pragma unroll
    for (int c = 0; c < 4; ++c)
      gA[c] = *(const floatx4*)&GsB[buf * 12288 + (w * 6 + c) * 256 + lane * 4];

#pragma unroll
    for (int s = 0; s < 2; ++s)
#pragma unroll
      for (int r = 0; r < 4; ++r) {
        float pre = acc[s][r] + gA[s][r];
        float g = __builtin_amdgcn_rcpf(1.f + __expf(-pre));
        rpk[wbase + s * 256 + r * 64] = (_Float16)(g * h_reg[s][r]);
      }
    float u_reg[2][4];
#pragma unroll
    for (int s = 0; s < 2; ++s)
#pragma unroll
      for (int r = 0; r < 4; ++r) {
        float pre = acc[2 + s][r] + gA[2 + s][r];
        u_reg[s][r] = __builtin_amdgcn_rcpf(1.f + __expf(-pre));
      }
    __builtin_amdgcn_s_waitcnt(WC_LGKM0);   // rpk visible
    __builtin_amdgcn_s_barrier();

    // ---------------- phase B: 2 candidate tiles --------------------------
    floatx4 accB[2] = {};
#pragma unroll
    for (int kt = 0; kt < 8; ++kt) {
      half8 a = *(const half8*)&rA[kt * 512];
#pragma unroll
      for (int s = 0; s < 2; ++s)
        accB[s] = __builtin_amdgcn_mfma_f32_16x16x32_f16(
            a, __builtin_bit_cast(half8, wc[s][kt]), accB[s], 0, 0, 0);
    }
    floatx4 gB[2];
#pragma unroll
    for (int s = 0; s < 2; ++s)
      gB[s] = *(const floatx4*)&GsB[buf * 12288 + (w * 6 + 4 + s) * 256 + lane * 4];

#pragma unroll
    for (int s = 0; s < 2; ++s)
#pragma unroll
      for (int r = 0; r < 4; ++r) {
        int row = quad * 4 + r;
        float pre = accB[s][r] + gB[s][r];
        float c = 1.f - 2.f * __builtin_amdgcn_rcpf(1.f + __expf(2.f * pre));
        float u = u_reg[s][r];
        float hn = u * h_reg[s][r] + (1.f - u) * c;
        bool valid = (t0 + t) < seq4[r];
        hn = valid ? hn : h_reg[s][r];
        h_reg[s][r] = hn;
        hpk[wbase + s * 256 + r * 64] = (_Float16)hn;
        if (outp)
          outp[((size_t)(rg * RPB + row) * tcl + t) * H_ + (w * 32 + s * 16 + l15)] =
              valid ? hn : 0.f;
      }
    __builtin_amdgcn_s_waitcnt(WC_LGKM0);   // hpk visible
    __builtin_amdgcn_s_barrier();
  }
  // --- save state from fp32 masters ---------------------------------------
#pragma unroll
  for (int s = 0; s < 2; ++s)
#pragma unroll
    for (int r = 0; r < 4; ++r)
      state[(size_t)(rg * RPB + quad * 4 + r) * H_ + (w * 32 + s * 16 + l15)] =
          h_reg[s][r];
}

// ---------------------------------------------------------------------------
// Final prediction: out[b, c] = [h_head | h_body] @ W_pred + b_pred.
// ---------------------------------------------------------------------------
__global__ __launch_bounds__(512) void pred_k(
    const float* __restrict__ hh, const float* __restrict__ hb,
    const float* __restrict__ Wp, const float* __restrict__ bpred,
    float* __restrict__ out)
{
  int tid = threadIdx.x;
  int b = tid >> 2, c = tid & 3;
  float acc = bpred[c];
  for (int k = 0; k < H_; ++k) acc += hh[b * H_ + k] * Wp[k * 4 + c];
  for (int k = 0; k < H_; ++k) acc += hb[b * H_ + k] * Wp[(H_ + k) * 4 + c];
  out[b * 4 + c] = acc;
}

// ---------------------------------------------------------------------------
extern "C" void kernel_launch(void* const* d_in, const int* in_sizes, int n_in,
                              void* d_out, int out_size, void* d_ws, size_t ws_size,
                              hipStream_t stream)
{
  (void)in_sizes; (void)n_in; (void)out_size;
  const int*   idsH = (const int*)  d_in[0];
  const int*   idsB = (const int*)  d_in[1];
  const float* emb  = (const float*)d_in[2];
  const float* Wp   = (const float*)d_in[3];
  const float* bp   = (const float*)d_in[4];
  const float* W[4][4];   // [hd0,hd1,bd0,bd1][Wg,bg,Wc,bc]
  for (int s = 0; s < 4; ++s)
    for (int q = 0; q < 4; ++q)
      W[s][q] = (const float*)d_in[5 + s * 4 + q];

  auto rnd = [](size_t n) { return (n + 255) & ~(size_t)255; };
  // exact workspace need (floats) for a given CH / rider config
  auto need = [&](int ch, bool rider) -> size_t {
    size_t s = 0;
    s += rnd(BATCH) * 2;                                       // seqH, seqB
    for (int i = 0; i < 4; ++i)
      s += rnd(NG) + rnd(98304) + rnd(122880);                 // bi, Wpk, Bxh
    s += rnd((size_t)BATCH * H_) * 4;                          // st0,stH0,hfH,hfB
    s += rnd((size_t)BATCH * ch * NG) * (rider ? 2 : 1);       // Gc0 (dbuf)
    s += rnd((size_t)BATCH * ch * NG);                         // Gc1
    s += rnd((size_t)BATCH * ch * H_);                         // Oc
    s += rnd((size_t)BATCH * TH_ * NG);                        // GH1
    s += rnd((size_t)BATCH * TH_ * H_);                        // OcH
    return s * 4;
  };

  int CH = 64;
  bool rider = need(64, true) <= ws_size;
  bool merged = rider || need(64, false) <= ws_size;
  if (!merged) {
    while (CH > 8 && need(CH, false) > ws_size) CH >>= 1;
    merged = (CH >= TH_);
  }
  const int CHH = (CH < TH_) ? CH : TH_;
  const int tcshB = __builtin_ctz(CH), tcshH = __builtin_ctz(CHH);

  float* wbase = (float*)d_ws;
  size_t off = 0;
  auto alloc = [&](size_t n) {
    float* p = wbase + off; off += rnd(n); return p;
  };
  int* seqH = (int*)alloc(BATCH);
  int* seqB = (int*)alloc(BATCH);
  float* bi[4]; _Float16* Wpk[4]; _Float16* Bxh[4];
  const int din[4] = {E_, H_, E_, H_};
  const int KT[4]  = {10, 8, 10, 8};        // ceil(din/32)
  for (int s = 0; s < 4; ++s) {
    bi[s]  = alloc(NG);
    Wpk[s] = (_Float16*)alloc(98304);        // 384 KB fp16
    Bxh[s] = (_Float16*)alloc(122880);       // 480 KB fp16
  }
  float* st0  = alloc((size_t)BATCH * H_);  // body layer-0 carry
  float* stH0 = alloc((size_t)BATCH * H_);  // head layer-0 carry (merged)
  float* hfH  = alloc((size_t)BATCH * H_);  // head layer-1 carry/final
  float* hfB  = alloc((size_t)BATCH * H_);  // body layer-1 carry/final
  float* Gc0b[2];
  Gc0b[0] = alloc((size_t)BATCH * CH * NG);
  Gc0b[1] = rider ? alloc((size_t)BATCH * CH * NG) : Gc0b[0];
  float* Gc1 = alloc((size_t)BATCH * CH * NG);
  float* Oc  = alloc((size_t)BATCH * CH * H_);
  float* GH1 = alloc((size_t)BATCH * TH_ * NG);
  float* OcH = alloc((size_t)BATCH * TH_ * H_);
  float* GH0 = Gc1;   // alias: Gc1 unused until gemm_L1(c0), which runs later

  // 1. pack weights
  for (int s = 0; s < 4; ++s) {
    pack_bias<<<(NG + 255) / 256, 256, 0, stream>>>(W[s][1], W[s][3], bi[s]);
    pack_w<<<(48 * 64 + 255) / 256, 256, 0, stream>>>(
        W[s][0], W[s][2], din[s], Wpk[s]);
    pack_bx<<<(KT[s] * 48 * 64 + 255) / 256, 256, 0, stream>>>(
        W[s][0], W[s][2], din[s], KT[s], Bxh[s]);
  }
  // 2. seqlens
  seq_k<<<BATCH, 256, 0, stream>>>(idsH, TH_, seqH);
  seq_k<<<BATCH, 256, 0, stream>>>(idsB, TB_, seqB);

  const int nbx = BATCH * CH / 64;                 // gemm M-tiles per chunk
  const int nrider = nbx * (NG / 128) / 2;         // rider blocks (2 tiles each)

  // gru dispatch: 3 jobs + optional gemm rider for next chunk's body L0
  auto gru3 = [&](const float* g0, const _Float16* w0, const int* x0, float* y0,
                  float* z0, int a0, int b0,
                  const float* g1, const _Float16* w1, const int* x1, float* y1,
                  float* z1, int a1, int b1,
                  const float* g2, const _Float16* w2, const int* x2, float* y2,
                  float* z2, int a2, int b2,
                  float* rG, int rt0) {
    int grid = 3 * NBLK + (rG ? nrider : 0);
    gru_pers<<<grid, 512, 0, stream>>>(g0, w0, x0, y0, z0, a0, b0,
                                       g1, w1, x1, y1, z1, a1, b1,
                                       g2, w2, x2, y2, z2, a2, b2,
                                       idsB, emb, Bxh[2], bi[2],
                                       rG, KT[2], rt0, tcshB, TB_, nbx);
  };

  if (merged) {
    // 3a. headline rides as job-2 inside the first two body dispatches;
    //     next-chunk body-L0 gemm rides as extra blocks (if ws allows).
    dim3 ggH(BATCH * TH_ / 64, NG / 128);
    gemm_mfma<<<ggH, 256, 0, stream>>>(nullptr, idsH, emb, Bxh[0], bi[0],
                                       GH0, E_, KT[0], 0, 5, TH_);
    const int nch = TB_ / CH;
    dim3 gg(nbx, NG / 128);
    gemm_mfma<<<gg, 256, 0, stream>>>(nullptr, idsB, emb, Bxh[2], bi[2],
                                      Gc0b[0], E_, KT[2], 0, tcshB, TB_);
    for (int c = 0; c < nch; ++c) {
      int t0 = c * CH;
      if (!rider && c > 0)   // no rider: serial gemmL0 per chunk
        gemm_mfma<<<gg, 256, 0, stream>>>(nullptr, idsB, emb, Bxh[2], bi[2],
                                          Gc0b[0], E_, KT[2], t0, tcshB, TB_);
      const float* g2 = (c == 0) ? GH0 : (c == 1) ? GH1 : nullptr;
      bool ride = rider && (c + 1 < nch);
      gru3(Gc0b[rider ? (c & 1) : 0], Wpk[2], seqB, Oc, st0, t0, CH,
           (c > 0) ? Gc1 : nullptr, Wpk[3], seqB, nullptr, hfB, (c - 1) * CH, CH,
           g2, Wpk[(c == 0) ? 0 : 1], seqH,
           (c == 0) ? OcH : nullptr, (c == 0) ? stH0 : hfH, 0, TH_,
           ride ? Gc0b[(c + 1) & 1] : nullptr, (c + 1) * CH);
      if (c == 0)
        gemm_mfma<<<ggH, 256, 0, stream>>>(OcH, nullptr, nullptr, Bxh[1], bi[1],
                                           GH1, H_, KT[1], 0, 5, TH_);
      gemm_mfma<<<gg, 256, 0, stream>>>(Oc, nullptr, nullptr, Bxh[3], bi[3],
                                        Gc1, H_, KT[3], 0, tcshB, TB_);
    }
    // drain: last body layer-1 chunk (no rider)
    gru3(nullptr, Wpk[2], seqB, nullptr, st0, 0, CH,
         Gc1, Wpk[3], seqB, nullptr, hfB, (nch - 1) * CH, CH,
         nullptr, Wpk[1], seqH, nullptr, hfH, 0, TH_,
         nullptr, 0);
  } else {
    // 3b. fallback: serial per-stream chunk pipeline
    auto run_stream = [&](const int* ids, int T, int chs, int tcsh,
                          const int* seq, int l0, int l1, float* hf) {
      int nchunks = T / chs;
      dim3 gg2(BATCH * chs / 64, NG / 128);
      for (int c = 0; c < nchunks; ++c) {
        int t0 = c * chs;
        gemm_mfma<<<gg2, 256, 0, stream>>>(nullptr, ids, emb, Bxh[l0], bi[l0],
                                           Gc0b[0], E_, KT[l0], t0, tcsh, T);
        gru3(Gc0b[0], Wpk[l0], seq, Oc, st0, t0, chs,
             (c > 0) ? Gc1 : nullptr, Wpk[l1], seq, nullptr, hf, (c - 1) * chs, chs,
             nullptr, Wpk[l1], seq, nullptr, hf, 0, chs,
             nullptr, 0);
        gemm_mfma<<<gg2, 256, 0, stream>>>(Oc, nullptr, nullptr, Bxh[l1], bi[l1],
                                           Gc1, H_, KT[l1], 0, tcsh, T);
      }
      gru3(nullptr, Wpk[l0], seq, nullptr, st0, 0, chs,
           Gc1, Wpk[l1], seq, nullptr, hf, (nchunks - 1) * chs, chs,
           nullptr, Wpk[l1], seq, nullptr, hf, 0, chs,
           nullptr, 0);
    };
    run_stream(idsH, TH_, CHH, tcshH, seqH, 0, 1, hfH);   // headline
    run_stream(idsB, TB_, CH,  tcshB, seqB, 2, 3, hfB);   // body
  }

  // 4. prediction head
  pred_k<<<1, 512, 0, stream>>>(hfH, hfB, Wp, bp, (float*)d_out);
}

// Round 3
// 2275.350 us; speedup vs baseline: 1.4050x; 1.1297x over previous
//
#include <hip/hip_runtime.h>
#include <cstdint>
#include <cstddef>

// Problem constants: V=50000, E=300, NF=1, H=256, B=128, TH=32, TB=512, NC=4.
#define H_    256
#define NG    768      // 512 gate cols (r|u) + 256 candidate cols, packed
#define BATCH 128
#define TH_   32
#define TB_   512
#define E_    300
#define RPB   16             // batch rows per gru block
#define NBLK  (BATCH / RPB)  // 8 row-groups per job; gru portion = 24 blocks (3 jobs)

typedef _Float16 half8 __attribute__((ext_vector_type(8)));
typedef float    floatx4 __attribute__((ext_vector_type(4)));

#define AS1 __attribute__((address_space(1)))
#define AS3 __attribute__((address_space(3)))

// s_waitcnt immediates (gfx9 encoding: vmcnt[3:0]=imm[3:0], vmcnt[5:4]=imm[15:14],
// expcnt=imm[6:4], lgkmcnt=imm[11:8]).
#define WC_LGKM0 0xC07F   // lgkmcnt(0), vmcnt/exp unconstrained
#define WC_VM14  0x0F7E   // vmcnt(14) only
#define WC_VM6   0x0F76   // vmcnt(6)  only
#define WC_VM0   0x0F70   // vmcnt(0)  only

// ---------------------------------------------------------------------------
// Fused packing + seqlen kernel (one dispatch replaces 14).
// blocks [0,256): seqlen (128 headline rows, 128 body rows).
// blocks [256,...): flat index over {bias, pack_w, pack_bx} x 4 layers.
// ---------------------------------------------------------------------------
__device__ __forceinline__ void d_bias(const float* bg, const float* bc,
                                       float* bias, int idx)
{
  bias[idx] = (idx < 2 * H_) ? bg[idx] : bc[idx - 2 * H_];
}

__device__ __forceinline__ void d_packw(const float* Wg, const float* Wc,
                                        int din, _Float16* wpk, int idx)
{
  int tile = idx >> 6, lane = idx & 63;
  int grp = tile >> 4, tt = tile & 15;
  int wv = tt >> 1, s = tt & 1;
  const float* W; int ncols, n0;
  if (grp == 0)      { W = Wg; ncols = 2 * H_; n0 = wv * 32 + s * 16; }
  else if (grp == 1) { W = Wg; ncols = 2 * H_; n0 = 256 + wv * 32 + s * 16; }
  else               { W = Wc; ncols = H_;     n0 = wv * 32 + s * 16; }
  int n = n0 + (lane & 15);
  int kb = (lane >> 4) * 8;
#pragma unroll
  for (int kt = 0; kt < 8; ++kt) {
    _Float16* dst = wpk + ((size_t)(tile * 8 + kt) * 64 + lane) * 8;
#pragma unroll
    for (int j = 0; j < 8; ++j)
      dst[j] = (_Float16)W[(size_t)(din + kt * 32 + kb + j) * ncols + n];
  }
}

__device__ __forceinline__ void d_packbx(const float* Wg, const float* Wc,
                                         int din, int KT, _Float16* out, int idx)
{
  int lane = idx & 63, tile = idx >> 6;
  int kt = tile / 48, nt = tile - kt * 48;
  int col = nt * 16 + (lane & 15);
  int k0 = kt * 32 + (lane >> 4) * 8;
  const float* W; int ncols, c2;
  if (col < 2 * H_) { W = Wg; ncols = 2 * H_; c2 = col; }
  else              { W = Wc; ncols = H_;     c2 = col - 2 * H_; }
  _Float16* dst = out + ((size_t)(kt * 48 + nt) * 64 + lane) * 8;
#pragma unroll
  for (int j = 0; j < 8; ++j) {
    int k = k0 + j;
    dst[j] = (k < din) ? (_Float16)W[(size_t)k * ncols + c2] : (_Float16)0.f;
  }
}

__global__ __launch_bounds__(256) void pack_all(
    const int* __restrict__ idsH, const int* __restrict__ idsB,
    int* __restrict__ seqH, int* __restrict__ seqB,
    const float* Wg0, const float* bg0, const float* Wc0, const float* bc0,
    const float* Wg1, const float* bg1, const float* Wc1, const float* bc1,
    const float* Wg2, const float* bg2, const float* Wc2, const float* bc2,
    const float* Wg3, const float* bg3, const float* Wc3, const float* bc3,
    float* bi0, float* bi1, float* bi2, float* bi3,
    _Float16* w0, _Float16* w1, _Float16* w2, _Float16* w3,
    _Float16* x0, _Float16* x1, _Float16* x2, _Float16* x3)
{
  int blk = blockIdx.x, tid = threadIdx.x;
  if (blk < 256) {
    __shared__ int red[256];
    const int* ids = (blk < 128) ? idsH : idsB;
    int T = (blk < 128) ? TH_ : TB_;
    int* seq = (blk < 128) ? seqH : seqB;
    int b = blk & 127;
    int cnt = 0;
    for (int t = tid; t < T; t += 256) cnt += (ids[b * T + t] != 0) ? 1 : 0;
    red[tid] = cnt;
    __syncthreads();
    for (int s = 128; s > 0; s >>= 1) {
      if (tid < s) red[tid] += red[tid + s];
      __syncthreads();
    }
    if (tid == 0) seq[b] = red[0];
    return;
  }
  int idx = (blk - 256) * 256 + tid;
  const float* Wg[4] = {Wg0, Wg1, Wg2, Wg3};
  const float* bg[4] = {bg0, bg1, bg2, bg3};
  const float* Wc[4] = {Wc0, Wc1, Wc2, Wc3};
  const float* bc[4] = {bc0, bc1, bc2, bc3};
  float* bi[4] = {bi0, bi1, bi2, bi3};
  _Float16* wp[4] = {w0, w1, w2, w3};
  _Float16* bx[4] = {x0, x1, x2, x3};
  const int din[4] = {E_, H_, E_, H_};
  const int KT[4] = {10, 8, 10, 8};
#pragma unroll
  for (int s = 0; s < 4; ++s) {
    if (idx < NG) { d_bias(bg[s], bc[s], bi[s], idx); return; }
    idx -= NG;
    if (idx < 48 * 64) { d_packw(Wg[s], Wc[s], din[s], wp[s], idx); return; }
    idx -= 48 * 64;
    int szx = KT[s] * 48 * 64;
    if (idx < szx) { d_packbx(Wg[s], Wc[s], din[s], KT[s], bx[s], idx); return; }
    idx -= szx;
  }
}

// ---------------------------------------------------------------------------
// MFMA input-projection GEMM (standalone; used upfront + fallback paths).
// Block 256 thr (4 waves), tile M=64 x N=128, K in 32-ktiles (KT of them).
// Output: fragment-packed G (R9-validated layout, consumed by gru_pers).
// ---------------------------------------------------------------------------
__global__ __launch_bounds__(256) void gemm_mfma(
    const float* __restrict__ Adir, const int* __restrict__ ids,
    const float* __restrict__ emb,
    const _Float16* __restrict__ Bpk, const float* __restrict__ bias,
    float* __restrict__ G, int K, int KT, int t0, int tcsh, int T)
{
  __shared__ __align__(16) _Float16 Al[2][64 * 40];
  __shared__ __align__(16) _Float16 Bl[2][8 * 512];
  const int tid = threadIdx.x;
  const int w = tid >> 6, lane = tid & 63;
  const int quad = lane >> 4, l15 = lane & 15;
  const int m0 = blockIdx.x * 64;
  const int n0 = blockIdx.y * 128;
  const int tc = 1 << tcsh;

  const int am = tid >> 2, akq = tid & 3;
  const int arow = m0 + am;
  const float* asrc;
  if (Adir) {
    asrc = Adir + (size_t)arow * K;
  } else {
    int b = arow >> tcsh, tl = arow & (tc - 1);
    asrc = emb + (size_t)ids[b * T + t0 + tl] * K;
  }

  float a8[8];
  auto loadA = [&](int kt) {
    int k0 = kt * 32 + akq * 8;
#pragma unroll
    for (int j = 0; j < 8; ++j) a8[j] = (k0 + j < K) ? asrc[k0 + j] : 0.f;
  };
  auto writeA = [&](int buf) {
    half8 v;
#pragma unroll
    for (int j = 0; j < 8; ++j) v[j] = (_Float16)a8[j];
    *(half8*)&Al[buf][am * 40 + akq * 8] = v;
  };
  auto stageB = [&](int kt, int buf) {
#pragma unroll
    for (int i = 0; i < 2; ++i) {
      int nt = (n0 >> 4) + w * 2 + i;
      const _Float16* src = Bpk + ((size_t)(kt * 48 + nt) * 64 + lane) * 8;
      __builtin_amdgcn_global_load_lds(
          (const AS1 unsigned int*)src,
          (AS3 unsigned int*)&Bl[buf][(w * 2 + i) * 512 + lane * 8], 16, 0, 0);
    }
  };

  loadA(0);
  stageB(0, 0);
  writeA(0);
  floatx4 acc[4][2] = {};

  for (int kt = 0; kt < KT; ++kt) {
    const int buf = kt & 1;
    __syncthreads();
    if (kt + 1 < KT) { loadA(kt + 1); stageB(kt + 1, buf ^ 1); }
    half8 bf0 = *(const half8*)&Bl[buf][(w * 2 + 0) * 512 + lane * 8];
    half8 bf1 = *(const half8*)&Bl[buf][(w * 2 + 1) * 512 + lane * 8];
#pragma unroll
    for (int st = 0; st < 4; ++st) {
      half8 af = *(const half8*)&Al[buf][(st * 16 + l15) * 40 + quad * 8];
      acc[st][0] = __builtin_amdgcn_mfma_f32_16x16x32_f16(af, bf0, acc[st][0], 0, 0, 0);
      acc[st][1] = __builtin_amdgcn_mfma_f32_16x16x32_f16(af, bf1, acc[st][1], 0, 0, 0);
    }
    if (kt + 1 < KT) writeA(buf ^ 1);
  }

  float bb[2] = { bias[n0 + w * 32 + l15], bias[n0 + w * 32 + 16 + l15] };
#pragma unroll
  for (int s = 0; s < 2; ++s) {
    int col = n0 + w * 32 + s * 16 + l15;
    int g = col >> 8, kk = col & 255;
    int ww = kk >> 5, ss = (kk >> 4) & 1, ll = kk & 15;
    int cc = 2 * g + ss;
#pragma unroll
    for (int st = 0; st < 4; ++st) {
#pragma unroll
      for (int r = 0; r < 4; ++r) {
        int grow = m0 + st * 16 + quad * 4 + r;
        int b = grow >> tcsh, tl = grow & (tc - 1);
        int rg = b >> 4, mm = b & 15, qb = mm >> 2, rb = mm & 3;
        G[((size_t)tl * BATCH + rg * RPB) * NG +
          ((ww * 6 + cc) * 64 + qb * 16 + ll) * 4 + rb] = acc[st][s][r] + bb[s];
      }
    }
  }
}

// ---------------------------------------------------------------------------
// Persistent-weight fused GRU (R9 internals unchanged) with THREE gru job
// slots + THREE gemm rider slots. gru blocks = ids 0..23; rider blocks
// follow, partitioned by the three riders' block counts. Each 512-thr rider
// block computes two independent M64xN128 gemm tiles (one per 256-thr half).
// Riders are fully independent of the gru jobs within the dispatch (their
// outputs are consumed >= 1 dispatch later); they hide on idle CUs.
// ---------------------------------------------------------------------------
__global__ __launch_bounds__(512, 1) void gru_pers(
    const float* __restrict__ G0, const _Float16* __restrict__ W0,
    const int* __restrict__ q0, float* __restrict__ o0, float* __restrict__ s0,
    int t00, int tc0,
    const float* __restrict__ G1, const _Float16* __restrict__ W1,
    const int* __restrict__ q1, float* __restrict__ o1, float* __restrict__ s1,
    int t01, int tc1,
    const float* __restrict__ G2, const _Float16* __restrict__ W2,
    const int* __restrict__ q2, float* __restrict__ o2, float* __restrict__ s2,
    int t02, int tc2,
    const float* rA_A, const int* rA_ids, const _Float16* rA_B,
    const float* rA_bi, float* rA_G, int rA_K, int rA_KT, int rA_t0,
    int rA_nbx, int rA_nblk,
    const float* rB_A, const int* rB_ids, const _Float16* rB_B,
    const float* rB_bi, float* rB_G, int rB_K, int rB_KT, int rB_t0,
    int rB_nbx, int rB_nblk,
    const float* rC_A, const int* rC_ids, const _Float16* rC_B,
    const float* rC_bi, float* rC_G, int rC_K, int rC_KT, int rC_t0,
    int rC_nbx, int rC_nblk,
    const float* __restrict__ r_emb, int r_tcsh, int r_T)
{
  __shared__ __align__(16) char smem[114688];

  const int tid = threadIdx.x;

  if (blockIdx.x >= 3 * NBLK) {
    // ================= GEMM RIDER: two tiles per 512-thr block ============
    int rb = blockIdx.x - 3 * NBLK;
    const float* Adir; const int* ids; const _Float16* Bpk; const float* bias;
    float* G; int K, KT, t0, nbx;
    if (rb < rA_nblk) {
      Adir = rA_A; ids = rA_ids; Bpk = rA_B; bias = rA_bi; G = rA_G;
      K = rA_K; KT = rA_KT; t0 = rA_t0; nbx = rA_nbx;
    } else if (rb < rA_nblk + rB_nblk) {
      rb -= rA_nblk;
      Adir = rB_A; ids = rB_ids; Bpk = rB_B; bias = rB_bi; G = rB_G;
      K = rB_K; KT = rB_KT; t0 = rB_t0; nbx = rB_nbx;
    } else {
      rb -= rA_nblk + rB_nblk;
      Adir = rC_A; ids = rC_ids; Bpk = rC_B; bias = rC_bi; G = rC_G;
      K = rC_K; KT = rC_KT; t0 = rC_t0; nbx = rC_nbx;
    }
    const int half = tid >> 8;
    _Float16* Al = (_Float16*)(smem + half * 10240);           // [2][2560]
    _Float16* Bl = (_Float16*)(smem + 20480 + half * 16384);   // [2][4096]
    const int t256 = tid & 255;
    const int w4 = (tid >> 6) & 3, lane = tid & 63;
    const int quad = lane >> 4, l15 = lane & 15;
    const int tidx = rb * 2 + half;
    const int bx = tidx % nbx, by = tidx / nbx;
    const int m0 = bx * 64, n0 = by * 128;
    const int tc = 1 << r_tcsh;

    const int am = t256 >> 2, akq = t256 & 3;
    const int arow = m0 + am;
    const float* asrc;
    if (Adir) {
      asrc = Adir + (size_t)arow * K;
    } else {
      int ab = arow >> r_tcsh, atl = arow & (tc - 1);
      asrc = r_emb + (size_t)ids[ab * r_T + t0 + atl] * K;
    }

    float a8[8];
    auto loadA = [&](int kt) {
      int k0 = kt * 32 + akq * 8;
#pragma unroll
      for (int j = 0; j < 8; ++j) a8[j] = (k0 + j < K) ? asrc[k0 + j] : 0.f;
    };
    auto writeA = [&](int buf) {
      half8 v;
#pragma unroll
      for (int j = 0; j < 8; ++j) v[j] = (_Float16)a8[j];
      *(half8*)&Al[buf * 2560 + am * 40 + akq * 8] = v;
    };
    auto stageB = [&](int kt, int buf) {
#pragma unroll
      for (int i = 0; i < 2; ++i) {
        int nt = (n0 >> 4) + w4 * 2 + i;
        const _Float16* src = Bpk + ((size_t)(kt * 48 + nt) * 64 + lane) * 8;
        __builtin_amdgcn_global_load_lds(
            (const AS1 unsigned int*)src,
            (AS3 unsigned int*)&Bl[buf * 4096 + (w4 * 2 + i) * 512 + lane * 8],
            16, 0, 0);
      }
    };

    loadA(0);
    stageB(0, 0);
    writeA(0);
    floatx4 acc[4][2] = {};

    for (int kt = 0; kt < KT; ++kt) {
      const int buf = kt & 1;
      __syncthreads();
      if (kt + 1 < KT) { loadA(kt + 1); stageB(kt + 1, buf ^ 1); }
      half8 bf0 = *(const half8*)&Bl[buf * 4096 + (w4 * 2 + 0) * 512 + lane * 8];
      half8 bf1 = *(const half8*)&Bl[buf * 4096 + (w4 * 2 + 1) * 512 + lane * 8];
#pragma unroll
      for (int st = 0; st < 4; ++st) {
        half8 af = *(const half8*)&Al[buf * 2560 + (st * 16 + l15) * 40 + quad * 8];
        acc[st][0] = __builtin_amdgcn_mfma_f32_16x16x32_f16(af, bf0, acc[st][0], 0, 0, 0);
        acc[st][1] = __builtin_amdgcn_mfma_f32_16x16x32_f16(af, bf1, acc[st][1], 0, 0, 0);
      }
      if (kt + 1 < KT) writeA(buf ^ 1);
    }

    float bb[2] = { bias[n0 + w4 * 32 + l15], bias[n0 + w4 * 32 + 16 + l15] };
#pragma unroll
    for (int s = 0; s < 2; ++s) {
      int col = n0 + w4 * 32 + s * 16 + l15;
      int g = col >> 8, kk = col & 255;
      int ww = kk >> 5, ss = (kk >> 4) & 1, ll = kk & 15;
      int cc = 2 * g + ss;
#pragma unroll
      for (int st = 0; st < 4; ++st) {
#pragma unroll
        for (int r = 0; r < 4; ++r) {
          int grow = m0 + st * 16 + quad * 4 + r;
          int b = grow >> r_tcsh, tl = grow & (tc - 1);
          int rg2 = b >> 4, mm = b & 15, qb = mm >> 2, rb2 = mm & 3;
          G[((size_t)tl * BATCH + rg2 * RPB) * NG +
            ((ww * 6 + cc) * 64 + qb * 16 + ll) * 4 + rb2] = acc[st][s][r] + bb[s];
        }
      }
    }
    return;
  }

  // ===================== GRU path (R9 internals unchanged) ================
  _Float16* hpk = (_Float16*)smem;              // 4096 halves
  _Float16* rpk = (_Float16*)(smem + 8192);     // 4096 halves
  float* GsB = (float*)(smem + 16384);          // [2][12288] floats

  const int job = blockIdx.x >> 3, rg = blockIdx.x & 7;
  const float* G; const _Float16* Wsrc; const int* seq;
  float* outp; float* state; int t0, tcl;
  if (job == 0)      { G = G0; Wsrc = W0; seq = q0; outp = o0; state = s0; t0 = t00; tcl = tc0; }
  else if (job == 1) { G = G1; Wsrc = W1; seq = q1; outp = o1; state = s1; t0 = t01; tcl = tc1; }
  else               { G = G2; Wsrc = W2; seq = q2; outp = o2; state = s2; t0 = t02; tcl = tc2; }
  if (!G) return;

  const int w = tid >> 6, lane = tid & 63;
  const int quad = lane >> 4, l15 = lane & 15;

  // --- load weights once; pin (blocks rematerialization/sinking) ----------
  floatx4 wg[4][8];   // gate tiles -> VGPRs
  floatx4 wc[2][8];   // candidate tiles -> AGPRs
#pragma unroll
  for (int i = 0; i < 4; ++i) {
    const int tile = (i >> 1) * 16 + w * 2 + (i & 1);
#pragma unroll
    for (int kt = 0; kt < 8; ++kt) {
      wg[i][kt] = *(const floatx4*)&Wsrc[((size_t)(tile * 8 + kt) * 64 + lane) * 8];
      asm volatile("" : "+v"(wg[i][kt]));
    }
  }
#pragma unroll
  for (int i = 0; i < 2; ++i) {
    const int tile = 32 + w * 2 + i;
#pragma unroll
    for (int kt = 0; kt < 8; ++kt) {
      wc[i][kt] = *(const floatx4*)&Wsrc[((size_t)(tile * 8 + kt) * 64 + lane) * 8];
      asm volatile("" : "+a"(wc[i][kt]));
    }
  }

  // --- seq / steps ---------------------------------------------------------
  int seq4[4];
#pragma unroll
  for (int r = 0; r < 4; ++r) seq4[r] = seq[rg * RPB + quad * 4 + r];
  int Smax = 0;
#pragma unroll
  for (int i = 0; i < 16; ++i) Smax = max(Smax, seq[rg * RPB + i]);
  int steps = Smax - t0;
  if (steps < 0) steps = 0;
  if (steps > tcl) steps = tcl;

  // --- frag addressing (R7-validated bank-exact layout) --------------------
  const int wbase = (w * 64 + quad * 2 + (l15 >> 3)) * 8 + (l15 & 7);
  const int rbase = (((quad >> 1) << 5) + ((l15 & 3) << 3) +
                     ((l15 >> 2) << 1) + (quad & 1)) * 8;

  // --- h_reg init + h frag fill -------------------------------------------
  float h_reg[2][4];
#pragma unroll
  for (int s = 0; s < 2; ++s)
#pragma unroll
    for (int r = 0; r < 4; ++r) {
      int row = quad * 4 + r, k = w * 32 + s * 16 + l15;
      float v = (t0 == 0) ? 0.f : state[(size_t)(rg * RPB + row) * H_ + k];
      h_reg[s][r] = v;
      hpk[wbase + s * 256 + r * 64] = (_Float16)v;
    }

  // --- async G staging: wave w copies its own 6 chunks (1 KB each) --------
  const float* gblk = G + (size_t)rg * RPB * NG + w * (6 * 256);
  float* ldsw = GsB + w * (6 * 256);
  auto stage = [&](int t, int buf) {
    const float* gp = gblk + (size_t)t * BATCH * NG;
    float* lp = ldsw + buf * 12288;
#pragma unroll
    for (int c = 0; c < 6; ++c) {
      __builtin_amdgcn_global_load_lds(
          (const AS1 unsigned int*)(gp + c * 256 + lane * 4),
          (AS3 unsigned int*)(lp + c * 256), 16, 0, 0);
    }
  };
  if (steps > 0) stage(0, 0);
  __syncthreads();   // one full drain: loads for t=0 complete + hpk visible

  const _Float16* hA = &hpk[rbase];
  const _Float16* rA = &rpk[rbase];

  for (int t = 0; t < steps; ++t) {
    const int buf = t & 1;
    const bool staged = (t + 1 < steps);
    if (staged) stage(t + 1, buf ^ 1);   // async prefetch next step's G

    // ---------------- phase A: 4 gate tiles (r s=0,1 ; u s=0,1) ----------
    floatx4 acc[4] = {};
#pragma unroll
    for (int kt = 0; kt < 8; ++kt) {
      half8 a = *(const half8*)&hA[kt * 512];
#pragma unroll
      for (int s = 0; s < 4; ++s)
        acc[s] = __builtin_amdgcn_mfma_f32_16x16x32_f16(
            a, __builtin_bit_cast(half8, wg[s][kt]), acc[s], 0, 0, 0);
    }

    if (staged) {
      if (outp) __builtin_amdgcn_s_waitcnt(WC_VM14);
      else      __builtin_amdgcn_s_waitcnt(WC_VM6);
    } else {
      __builtin_amdgcn_s_waitcnt(WC_VM0);
    }

    floatx4 gA[4];
#pragma unroll
    for (int c = 0; c < 4; ++c)
      gA[c] = *(const floatx4*)&GsB[buf * 12288 + (w * 6 + c) * 256 + lane * 4];

#pragma unroll
    for (int s = 0; s < 2; ++s)
#pragma unroll
      for (int r = 0; r < 4; ++r) {
        float pre = acc[s][r] + gA[s][r];
        float g = __builtin_amdgcn_rcpf(1.f + __expf(-pre));
        rpk[wbase + s * 256 + r * 64] = (_Float16)(g * h_reg[s][r]);
      }
    float u_reg[2][4];
#pragma unroll
    for (int s = 0; s < 2; ++s)
#pragma unroll
      for (int r = 0; r < 4; ++r) {
        float pre = acc[2 + s][r] + gA[2 + s][r];
        u_reg[s][r] = __builtin_amdgcn_rcpf(1.f + __expf(-pre));
      }
    __builtin_amdgcn_s_waitcnt(WC_LGKM0);   // rpk visible
    __builtin_amdgcn_s_barrier();

    // ---------------- phase B: 2 candidate tiles --------------------------
    floatx4 accB[2] = {};
#pragma unroll
    for (int kt = 0; kt < 8; ++kt) {
      half8 a = *(const half8*)&rA[kt * 512];
#pragma unroll
      for (int s = 0; s < 2; ++s)
        accB[s] = __builtin_amdgcn_mfma_f32_16x16x32_f16(
            a, __builtin_bit_cast(half8, wc[s][kt]), accB[s], 0, 0, 0);
    }
    floatx4 gB[2];
#pragma unroll
    for (int s = 0; s < 2; ++s)
      gB[s] = *(const floatx4*)&GsB[buf * 12288 + (w * 6 + 4 + s) * 256 + lane * 4];

#pragma unroll
    for (int s = 0; s < 2; ++s)
#pragma unroll
      for (int r = 0; r < 4; ++r) {
        int row = quad * 4 + r;
        float pre = accB[s][r] + gB[s][r];
        float c = 1.f - 2.f * __builtin_amdgcn_rcpf(1.f + __expf(2.f * pre));
        float u = u_reg[s][r];
        float hn = u * h_reg[s][r] + (1.f - u) * c;
        bool valid = (t0 + t) < seq4[r];
        hn = valid ? hn : h_reg[s][r];
        h_reg[s][r] = hn;
        hpk[wbase + s * 256 + r * 64] = (_Float16)hn;
        if (outp)
          outp[((size_t)(rg * RPB + row) * tcl + t) * H_ + (w * 32 + s * 16 + l15)] =
              valid ? hn : 0.f;
      }
    __builtin_amdgcn_s_waitcnt(WC_LGKM0);   // hpk visible
    __builtin_amdgcn_s_barrier();
  }
  // --- save state from fp32 masters ---------------------------------------
#pragma unroll
  for (int s = 0; s < 2; ++s)
#pragma unroll
    for (int r = 0; r < 4; ++r)
      state[(size_t)(rg * RPB + quad * 4 + r) * H_ + (w * 32 + s * 16 + l15)] =
          h_reg[s][r];
}

// ---------------------------------------------------------------------------
// Final prediction: out[b, c] = [h_head | h_body] @ W_pred + b_pred.
// ---------------------------------------------------------------------------
__global__ __launch_bounds__(512) void pred_k(
    const float* __restrict__ hh, const float* __restrict__ hb,
    const float* __restrict__ Wp, const float* __restrict__ bpred,
    float* __restrict__ out)
{
  int tid = threadIdx.x;
  int b = tid >> 2, c = tid & 3;
  float acc = bpred[c];
  for (int k = 0; k < H_; ++k) acc += hh[b * H_ + k] * Wp[k * 4 + c];
  for (int k = 0; k < H_; ++k) acc += hb[b * H_ + k] * Wp[(H_ + k) * 4 + c];
  out[b * 4 + c] = acc;
}

// ---------------------------------------------------------------------------
extern "C" void kernel_launch(void* const* d_in, const int* in_sizes, int n_in,
                              void* d_out, int out_size, void* d_ws, size_t ws_size,
                              hipStream_t stream)
{
  (void)in_sizes; (void)n_in; (void)out_size;
  const int*   idsH = (const int*)  d_in[0];
  const int*   idsB = (const int*)  d_in[1];
  const float* emb  = (const float*)d_in[2];
  const float* Wp   = (const float*)d_in[3];
  const float* bp   = (const float*)d_in[4];
  const float* W[4][4];   // [hd0,hd1,bd0,bd1][Wg,bg,Wc,bc]
  for (int s = 0; s < 4; ++s)
    for (int q = 0; q < 4; ++q)
      W[s][q] = (const float*)d_in[5 + s * 4 + q];

  auto rnd = [](size_t n) { return (n + 255) & ~(size_t)255; };
  const size_t prefix_f =
      2 * rnd(BATCH) + 4 * (rnd(NG) + rnd(98304) + rnd(122880)) +
      4 * rnd((size_t)BATCH * H_);
  // FULL mode (CH=32, lag-2, all gemms ridden)
  auto need_full = [&]() -> size_t {
    size_t s = prefix_f;
    s += 2 * rnd((size_t)BATCH * 32 * NG);   // Gc0[2]
    s += 2 * rnd((size_t)BATCH * 32 * NG);   // Gc1[2]
    s += 2 * rnd((size_t)BATCH * 32 * H_);   // Oc[2]
    s += 2 * rnd((size_t)BATCH * TH_ * NG);  // GH0, GH1
    s += rnd((size_t)BATCH * TH_ * H_);      // OcH
    return s * 4;
  };
  // R2 mode (CH=64, lag-1, gemmL0 ridden, gemmL1 serial)
  auto need_r2 = [&](int ch, bool rider) -> size_t {
    size_t s = prefix_f;
    s += rnd((size_t)BATCH * ch * NG) * (rider ? 2 : 1);   // Gc0
    s += rnd((size_t)BATCH * ch * NG);                     // Gc1
    s += rnd((size_t)BATCH * ch * H_);                     // Oc
    s += rnd((size_t)BATCH * TH_ * NG);                    // GH1
    s += rnd((size_t)BATCH * TH_ * H_);                    // OcH
    return s * 4;
  };

  enum { M_FULL, M_R2, M_SERIAL } mode;
  int CH = 64; bool rider = false;
  if (need_full() <= ws_size) { mode = M_FULL; CH = 32; }
  else if (need_r2(64, true) <= ws_size) { mode = M_R2; CH = 64; rider = true; }
  else {
    CH = 64;
    while (CH > 8 && need_r2(CH, false) > ws_size) CH >>= 1;
    mode = (CH >= TH_) ? M_R2 : M_SERIAL;
  }
  const int CHH = (CH < TH_) ? CH : TH_;
  const int tcshB = __builtin_ctz(CH), tcshH = __builtin_ctz(CHH);

  float* wbase = (float*)d_ws;
  size_t off = 0;
  auto alloc = [&](size_t n) {
    float* p = wbase + off; off += rnd(n); return p;
  };
  int* seqH = (int*)alloc(BATCH);
  int* seqB = (int*)alloc(BATCH);
  float* bi[4]; _Float16* Wpk[4]; _Float16* Bxh[4];
  const int KT[4]  = {10, 8, 10, 8};        // ceil(din/32)
  for (int s = 0; s < 4; ++s) {
    bi[s]  = alloc(NG);
    Wpk[s] = (_Float16*)alloc(98304);        // 384 KB fp16
    Bxh[s] = (_Float16*)alloc(122880);       // 480 KB fp16
  }
  float* st0  = alloc((size_t)BATCH * H_);  // body layer-0 carry
  float* stH0 = alloc((size_t)BATCH * H_);  // head layer-0 carry
  float* hfH  = alloc((size_t)BATCH * H_);  // head layer-1 carry/final
  float* hfB  = alloc((size_t)BATCH * H_);  // body layer-1 carry/final

  float *Gc0b[2], *Gc1b[2], *Ocb[2], *GH0, *GH1, *OcH;
  if (mode == M_FULL) {
    Gc0b[0] = alloc((size_t)BATCH * CH * NG);
    Gc0b[1] = alloc((size_t)BATCH * CH * NG);
    Gc1b[0] = alloc((size_t)BATCH * CH * NG);
    Gc1b[1] = alloc((size_t)BATCH * CH * NG);
    Ocb[0]  = alloc((size_t)BATCH * CH * H_);
    Ocb[1]  = alloc((size_t)BATCH * CH * H_);
    GH0     = alloc((size_t)BATCH * TH_ * NG);
    GH1     = alloc((size_t)BATCH * TH_ * NG);
    OcH     = alloc((size_t)BATCH * TH_ * H_);
  } else {
    Gc0b[0] = alloc((size_t)BATCH * CH * NG);
    Gc0b[1] = rider ? alloc((size_t)BATCH * CH * NG) : Gc0b[0];
    Gc1b[0] = Gc1b[1] = alloc((size_t)BATCH * CH * NG);
    Ocb[0]  = Ocb[1]  = alloc((size_t)BATCH * CH * H_);
    GH1     = alloc((size_t)BATCH * TH_ * NG);
    OcH     = alloc((size_t)BATCH * TH_ * H_);
    GH0     = Gc1b[0];   // alias (R2-validated): Gc1 unused until gemm_L1(c0)
  }

  // 1. fused packs + seqlens (one dispatch)
  {
    int packN = 0;
    for (int s = 0; s < 4; ++s) packN += NG + 48 * 64 + KT[s] * 48 * 64;
    int grid = 256 + (packN + 255) / 256;
    pack_all<<<grid, 256, 0, stream>>>(
        idsH, idsB, seqH, seqB,
        W[0][0], W[0][1], W[0][2], W[0][3],
        W[1][0], W[1][1], W[1][2], W[1][3],
        W[2][0], W[2][1], W[2][2], W[2][3],
        W[3][0], W[3][1], W[3][2], W[3][3],
        bi[0], bi[1], bi[2], bi[3],
        Wpk[0], Wpk[1], Wpk[2], Wpk[3],
        Bxh[0], Bxh[1], Bxh[2], Bxh[3]);
  }

  struct RJ {   // rider gemm job
    const float* A; const int* ids; const _Float16* B; const float* bi;
    float* G; int K, KT, t0, nbx, nblk;
  };
  auto gru_launch = [&](const float* g0, const _Float16* w0, const int* x0,
                        float* y0, float* z0, int a0, int b0,
                        const float* g1, const _Float16* w1, const int* x1,
                        float* y1, float* z1, int a1, int b1,
                        const float* g2, const _Float16* w2, const int* x2,
                        float* y2, float* z2, int a2, int b2,
                        RJ rA, RJ rB, RJ rC, int tcsh) {
    int grid = 3 * NBLK + rA.nblk + rB.nblk + rC.nblk;
    gru_pers<<<grid, 512, 0, stream>>>(
        g0, w0, x0, y0, z0, a0, b0,
        g1, w1, x1, y1, z1, a1, b1,
        g2, w2, x2, y2, z2, a2, b2,
        rA.A, rA.ids, rA.B, rA.bi, rA.G, rA.K, rA.KT, rA.t0, rA.nbx, rA.nblk,
        rB.A, rB.ids, rB.B, rB.bi, rB.G, rB.K, rB.KT, rB.t0, rB.nbx, rB.nblk,
        rC.A, rC.ids, rC.B, rC.bi, rC.G, rC.K, rC.KT, rC.t0, rC.nbx, rC.nblk,
        emb, tcsh, TB_);
  };
  const RJ RNULL = {nullptr, nullptr, nullptr, nullptr, nullptr, 0, 0, 0, 1, 0};

  if (mode == M_FULL) {
    // ---- CH=32, lag-2 pipeline; every gemm rides except the two seeds ----
    const int nch = TB_ / CH;                 // 16
    const int nbx = BATCH * CH / 64;          // 64
    const int nrb = nbx * (NG / 128) / 2;     // 192 rider blocks per gemm
    // seeds: Gc0(0), GH0
    gemm_mfma<<<dim3(nbx, NG / 128), 256, 0, stream>>>(
        nullptr, idsB, emb, Bxh[2], bi[2], Gc0b[0], E_, KT[2], 0, tcshB, TB_);
    gemm_mfma<<<dim3(BATCH * TH_ / 64, NG / 128), 256, 0, stream>>>(
        nullptr, idsH, emb, Bxh[0], bi[0], GH0, E_, KT[0], 0, tcshH, TH_);

    for (int c = 0; c <= nch + 1; ++c) {
      // job0: body L0 chunk c
      const float* g0 = (c < nch) ? Gc0b[c & 1] : nullptr;
      // job1: body L1 chunk c-2
      const float* g1 = (c >= 2) ? Gc1b[c & 1] : nullptr;   // (c-2)&1 == c&1
      // job2: head L0 at c=0, head L1 at c=2
      const float* g2 = (c == 0) ? GH0 : (c == 2) ? GH1 : nullptr;
      // riderA: gemmL0(c+1) (emb-gather)
      RJ rA = RNULL, rB = RNULL, rC = RNULL;
      if (c + 1 < nch)
        rA = {nullptr, idsB, Bxh[2], bi[2], Gc0b[(c + 1) & 1],
              E_, KT[2], (c + 1) * CH, nbx, nrb};
      // riderB: gemmL1(c-1) from Oc
      if (c >= 1 && c <= nch)
        rB = {Ocb[(c - 1) & 1], nullptr, Bxh[3], bi[3], Gc1b[(c - 1) & 1],
              H_, KT[3], 0, nbx, nrb};
      // riderC: gemmH1 at c=1 (reads OcH from dispatch 0)
      if (c == 1)
        rC = {OcH, nullptr, Bxh[1], bi[1], GH1, H_, KT[1], 0,
              BATCH * TH_ / 64, (BATCH * TH_ / 64) * (NG / 128) / 2};

      gru_launch(
          g0, Wpk[2], seqB, (c < nch) ? Ocb[c & 1] : nullptr, st0, c * CH, CH,
          g1, Wpk[3], seqB, nullptr, hfB, (c - 2) * CH, CH,
          g2, Wpk[(c == 0) ? 0 : 1], seqH,
          (c == 0) ? OcH : nullptr, (c == 0) ? stH0 : hfH, 0, TH_,
          rA, rB, rC, tcshB);
    }
  } else if (mode == M_R2) {
    // ---- R2 schedule: CH>=32 merged head, lag-1, optional gemmL0 rider ---
    const int nch = TB_ / CH;
    const int nbx = BATCH * CH / 64;
    const int nrb = rider ? nbx * (NG / 128) / 2 : 0;
    dim3 ggH(BATCH * TH_ / 64, NG / 128);
    dim3 gg(nbx, NG / 128);
    gemm_mfma<<<ggH, 256, 0, stream>>>(nullptr, idsH, emb, Bxh[0], bi[0],
                                       GH0, E_, KT[0], 0, tcshH, TH_);
    gemm_mfma<<<gg, 256, 0, stream>>>(nullptr, idsB, emb, Bxh[2], bi[2],
                                      Gc0b[0], E_, KT[2], 0, tcshB, TB_);
    for (int c = 0; c < nch; ++c) {
      int t0 = c * CH;
      if (!rider && c > 0)
        gemm_mfma<<<gg, 256, 0, stream>>>(nullptr, idsB, emb, Bxh[2], bi[2],
                                          Gc0b[0], E_, KT[2], t0, tcshB, TB_);
      const float* g2 = (c == 0) ? GH0 : (c == 1) ? GH1 : nullptr;
      RJ rA = RNULL;
      if (rider && c + 1 < nch)
        rA = {nullptr, idsB, Bxh[2], bi[2], Gc0b[(c + 1) & 1],
              E_, KT[2], (c + 1) * CH, nbx, nrb};
      gru_launch(
          Gc0b[rider ? (c & 1) : 0], Wpk[2], seqB, Ocb[0], st0, t0, CH,
          (c > 0) ? Gc1b[0] : nullptr, Wpk[3], seqB, nullptr, hfB,
          (c - 1) * CH, CH,
          g2, Wpk[(c == 0) ? 0 : 1], seqH,
          (c == 0) ? OcH : nullptr, (c == 0) ? stH0 : hfH, 0, TH_,
          rA, RNULL, RNULL, tcshB);
      if (c == 0)
        gemm_mfma<<<ggH, 256, 0, stream>>>(OcH, nullptr, nullptr, Bxh[1], bi[1],
                                           GH1, H_, KT[1], 0, tcshH, TH_);
      gemm_mfma<<<gg, 256, 0, stream>>>(Ocb[0], nullptr, nullptr, Bxh[3], bi[3],
                                        Gc1b[0], H_, KT[3], 0, tcshB, TB_);
    }
    gru_launch(nullptr, Wpk[2], seqB, nullptr, st0, 0, CH,
               Gc1b[0], Wpk[3], seqB, nullptr, hfB, (nch - 1) * CH, CH,
               nullptr, Wpk[1], seqH, nullptr, hfH, 0, TH_,
               RNULL, RNULL, RNULL, tcshB);
  } else {
    // ---- serial per-stream fallback --------------------------------------
    auto run_stream = [&](const int* ids, int T, int chs, int tcsh,
                          const int* seq, int l0, int l1, float* hf) {
      int nchunks = T / chs;
      dim3 gg2(BATCH * chs / 64, NG / 128);
      for (int c = 0; c < nchunks; ++c) {
        int t0 = c * chs;
        gemm_mfma<<<gg2, 256, 0, stream>>>(nullptr, ids, emb, Bxh[l0], bi[l0],
                                           Gc0b[0], E_, KT[l0], t0, tcsh, T);
        gru_launch(Gc0b[0], Wpk[l0], seq, Ocb[0], st0, t0, chs,
                   (c > 0) ? Gc1b[0] : nullptr, Wpk[l1], seq, nullptr, hf,
                   (c - 1) * chs, chs,
                   nullptr, Wpk[l1], seq, nullptr, hf, 0, chs,
                   RNULL, RNULL, RNULL, tcsh);
        gemm_mfma<<<gg2, 256, 0, stream>>>(Ocb[0], nullptr, nullptr, Bxh[l1],
                                           bi[l1], Gc1b[0], H_, KT[l1], 0, tcsh, T);
      }
      gru_launch(nullptr, Wpk[l0], seq, nullptr, st0, 0, chs,
                 Gc1b[0], Wpk[l1], seq, nullptr, hf, (nchunks - 1) * chs, chs,
                 nullptr, Wpk[l1], seq, nullptr, hf, 0, chs,
                 RNULL, RNULL, RNULL, tcsh);
    };
    run_stream(idsH, TH_, CHH, tcshH, seqH, 0, 1, hfH);   // headline
    run_stream(idsB, TB_, CH,  tcshB, seqB, 2, 3, hfB);   // body
  }

  // 4. prediction head
  pred_k<<<1, 512, 0, stream>>>(hfH, hfB, Wp, bp, (float*)d_out);
}